// Round 6
// baseline (1256.796 us; speedup 1.0000x reference)
//
#include <hip/hip_runtime.h>
#include <hip/hip_bf16.h>

#define N_NODES  50000
#define N_EDGES  800000
#define N_GRAPHS 64
#define EMB      24
#define MDIM     64
#define EDGE_IN  57
#define EH       114   // EDGE_IN*2
#define CH       256   // M_DIM*4
#define NIN      88    // EMB+MDIM
#define NH       48    // EMB*2
#define MLP      256
#define ETILE    128
#define NTILE    64

typedef __bf16 bf16_t;
typedef __bf16 bf16x8 __attribute__((ext_vector_type(8)));
typedef __bf16 bf16x4 __attribute__((ext_vector_type(4)));
typedef float  f32x4  __attribute__((ext_vector_type(4)));

__device__ __forceinline__ float siluf(float x) {
    return x * __builtin_amdgcn_rcpf(1.0f + __expf(-x));
}

// ---------------- embedding: feats0 = emb_table[z] @ emb_w + emb_b ----------
__global__ void embed_kernel(const int* __restrict__ z, const float* __restrict__ table,
                             const float* __restrict__ w, const float* __restrict__ b,
                             const int* __restrict__ batch, float* __restrict__ f0,
                             bf16_t* __restrict__ fb0, float* __restrict__ cnt)
{
    int n = blockIdx.x * blockDim.x + threadIdx.x;
    if (n >= N_NODES) return;
    float r[EMB];
    const float4* tr = reinterpret_cast<const float4*>(table + z[n] * EMB);
    #pragma unroll
    for (int q = 0; q < 6; q++) {
        float4 v = tr[q];
        r[q*4] = v.x; r[q*4+1] = v.y; r[q*4+2] = v.z; r[q*4+3] = v.w;
    }
    float o[EMB];
    #pragma unroll
    for (int j = 0; j < EMB; j++) o[j] = b[j];
    #pragma unroll
    for (int i = 0; i < EMB; i++) {
        #pragma unroll
        for (int j = 0; j < EMB; j++) o[j] = fmaf(r[i], w[i*EMB + j], o[j]);
    }
    float4* dst = reinterpret_cast<float4*>(f0 + (size_t)n * EMB);
    #pragma unroll
    for (int q = 0; q < 6; q++) dst[q] = make_float4(o[q*4], o[q*4+1], o[q*4+2], o[q*4+3]);
    bf16x8* bdst = reinterpret_cast<bf16x8*>(fb0 + (size_t)n * EMB);
    #pragma unroll
    for (int q = 0; q < 3; q++) {
        bf16x8 pk;
        #pragma unroll
        for (int j = 0; j < 8; j++) pk[j] = (bf16_t)o[q*8 + j];
        bdst[q] = pk;
    }
    atomicAdd(&cnt[batch[n]], 1.0f);
}

// ---------------- weight pre-pack to bf16 MFMA layout (A-operand [n][k]) ----
#define PK_W1   (128*64)
#define PK_W2   (64*128)
#define PK_CW   (256*64)
#define PK_F0   (256*128)
#define PK_FM   (256*256)
#define PK_TOT  (2*PK_W1 + 2*PK_W2 + PK_CW + PK_F0 + 2*PK_FM)
__global__ void pack_kernel(const float* __restrict__ ew1, const float* __restrict__ eb1,
                            const float* __restrict__ ew2, const float* __restrict__ eb2,
                            const float* __restrict__ cw1, const float* __restrict__ f0w,
                            const float* __restrict__ f1w, const float* __restrict__ f2w,
                            bf16_t* __restrict__ pw)
{
    int idx = blockIdx.x * blockDim.x + threadIdx.x;
    if (idx >= PK_TOT) return;
    float v = 0.0f;
    if (idx < 2 * PK_W1) {
        int l = idx / PK_W1, r = idx - l * PK_W1;
        int n = r >> 6, k = r & 63;
        if (n < EH && k < EDGE_IN)       v = ew1[(l * EDGE_IN + k) * EH + n];
        else if (n < EH && k == EDGE_IN) v = eb1[l * EH + n];
    } else if (idx < 2 * PK_W1 + 2 * PK_W2) {
        int r0 = idx - 2 * PK_W1;
        int l = r0 / PK_W2, r = r0 - l * PK_W2;
        int n = r >> 7, k = r & 127;
        if (k < EH)       v = ew2[(l * EH + k) * MDIM + n];
        else if (k == EH) v = eb2[l * MDIM + n];
    } else if (idx < 2 * PK_W1 + 2 * PK_W2 + PK_CW) {
        int r = idx - (2 * PK_W1 + 2 * PK_W2);
        int n = r >> 6, k = r & 63;
        v = cw1[k * CH + n];
    } else if (idx < 2 * PK_W1 + 2 * PK_W2 + PK_CW + PK_F0) {
        int r = idx - (2 * PK_W1 + 2 * PK_W2 + PK_CW);
        int n = r >> 7, k = r & 127;
        if (k < 72) v = f0w[k * MLP + n];
    } else {
        int r0 = idx - (2 * PK_W1 + 2 * PK_W2 + PK_CW + PK_F0);
        int l = r0 / PK_FM, r = r0 - l * PK_FM;
        int n = r >> 8, k = r & 255;
        v = (l == 0) ? f1w[k * MLP + n] : f2w[k * MLP + n];
    }
    pw[idx] = (bf16_t)v;
}

// ---------------- CSR build --------------------------------------------------
__global__ void hist_kernel(const int* __restrict__ dst, int* __restrict__ deg)
{
    int e = blockIdx.x * blockDim.x + threadIdx.x;
    if (e < N_EDGES) atomicAdd(&deg[dst[e]], 1);
}

__global__ __launch_bounds__(1024)
void scan_kernel(const int* __restrict__ deg, int* __restrict__ cursor)
{
    __shared__ int part[1024];
    int t = threadIdx.x;
    const int PER = 49;
    int base = t * PER;
    int s = 0;
    for (int i = 0; i < PER; i++) {
        int p = base + i;
        if (p < N_NODES) s += deg[p];
    }
    part[t] = s;
    __syncthreads();
    for (int off = 1; off < 1024; off <<= 1) {
        int add = (t >= off) ? part[t - off] : 0;
        __syncthreads();
        part[t] += add;
        __syncthreads();
    }
    int run = (t > 0) ? part[t - 1] : 0;
    for (int i = 0; i < PER; i++) {
        int p = base + i;
        if (p < N_NODES) { cursor[p] = run; run += deg[p]; }
    }
}

__global__ void scatter_kernel(const int* __restrict__ src, const int* __restrict__ dst,
                               int* __restrict__ cursor, int* __restrict__ srcs_s,
                               int* __restrict__ dsts_s)
{
    int e = blockIdx.x * blockDim.x + threadIdx.x;
    if (e >= N_EDGES) return;
    int d = dst[e];
    int pos = atomicAdd(&cursor[d], 1);
    srcs_s[pos] = src[e];
    dsts_s[pos] = d;
}

// ---------------- fused MFMA edge kernel (512 thr / 8 waves / 128 edges) ----
// A = weights [n][k] (global, L2-hot), B = data^T (LDS). D = out^T: lane holds
// 4 consecutive features of one edge. Each wave owns a 16-edge stripe.
// LDS union R1raw (32KB): Ein bf16 [128][64] -> H1 bf16 [128][128] ->
// M f32 [128][64]. Swizzle: 16B granule g at row e -> g ^ (e&7).
// 4 blocks x 8 waves = 32 waves/CU (100% cap).
template<int COOR>
__global__ __launch_bounds__(512, 8)
void edge_mfma(const bf16_t* __restrict__ fb, const float* __restrict__ coors,
               const int* __restrict__ srcs_s, const int* __restrict__ dsts_s,
               const bf16_t* __restrict__ W1t, const bf16_t* __restrict__ W2t,
               const bf16_t* __restrict__ CW1t, const float* __restrict__ cb1,
               const float* __restrict__ cw2, const float* __restrict__ cb2,
               float* __restrict__ m_i, float* __restrict__ cdelta)
{
    __shared__ __align__(16) char R1raw[ETILE * 64 * 4]; // 32KB
    __shared__ float s_rel[COOR ? ETILE * 3 : 4];
    __shared__ float s_cacc[COOR ? ETILE : 4];
    __shared__ int   s_dst[ETILE];
    bf16_t* R1 = (bf16_t*)R1raw;
    float*  Mf32 = (float*)R1raw;

    const int t = threadIdx.x;
    const int w = t >> 6;             // wave 0..7
    const int l = t & 63;
    const int row0 = w * 16;          // wave's 16-edge stripe
    const int ebase = blockIdx.x * ETILE;
    const int l15 = l & 15, l4 = l >> 4;

    // ---- gather: 4 threads per edge ----
    {
        int e_loc = t >> 2, part = t & 3;
        int e = ebase + e_loc;
        if (part == 0) {
            int d = dsts_s[e];
            s_dst[e_loc] = d;
            const bf16x8* fp = reinterpret_cast<const bf16x8*>(fb + (size_t)d * EMB);
            #pragma unroll
            for (int g = 0; g < 3; g++)
                *(bf16x8*)&R1[e_loc*64 + (g ^ (e_loc & 7))*8] = fp[g];
        } else if (part == 1) {
            int s = srcs_s[e];
            const bf16x8* fp = reinterpret_cast<const bf16x8*>(fb + (size_t)s * EMB);
            #pragma unroll
            for (int g = 0; g < 3; g++)
                *(bf16x8*)&R1[e_loc*64 + ((g + 3) ^ (e_loc & 7))*8] = fp[g];
        } else {
            int s = srcs_s[e], d = dsts_s[e];
            float rx = coors[s*3+0] - coors[d*3+0];
            float ry = coors[s*3+1] - coors[d*3+1];
            float rz = coors[s*3+2] - coors[d*3+2];
            float d2 = rx*rx + ry*ry + rz*rz;
            if (part == 2) {
                bf16x8 p6;
                p6[0]=(bf16_t)__sinf(d2);        p6[1]=(bf16_t)__sinf(d2*0.5f);
                p6[2]=(bf16_t)__sinf(d2*0.25f);  p6[3]=(bf16_t)__sinf(d2*0.125f);
                p6[4]=(bf16_t)__cosf(d2);        p6[5]=(bf16_t)__cosf(d2*0.5f);
                p6[6]=(bf16_t)__cosf(d2*0.25f);  p6[7]=(bf16_t)__cosf(d2*0.125f);
                *(bf16x8*)&R1[e_loc*64 + (6 ^ (e_loc & 7))*8] = p6;
            } else {
                if (COOR) { s_rel[e_loc*3+0] = rx; s_rel[e_loc*3+1] = ry; s_rel[e_loc*3+2] = rz; }
                bf16x8 p7;
                p7[0]=(bf16_t)d2; p7[1]=(bf16_t)1.0f;
                p7[2]=(bf16_t)0.f; p7[3]=(bf16_t)0.f; p7[4]=(bf16_t)0.f;
                p7[5]=(bf16_t)0.f; p7[6]=(bf16_t)0.f; p7[7]=(bf16_t)0.f;
                *(bf16x8*)&R1[e_loc*64 + (7 ^ (e_loc & 7))*8] = p7;
            }
        }
    }
    __syncthreads();

    // ---- GEMM1: H1^T[f][e] = W1t[f][k] * Ein^T[k][e] ----
    f32x4 acc1[8];
    #pragma unroll
    for (int ft = 0; ft < 8; ft++) acc1[ft] = (f32x4){0.f,0.f,0.f,0.f};
    #pragma unroll
    for (int ks = 0; ks < 2; ks++) {
        int e = row0 + l15;
        bf16x8 bfrag = *(const bf16x8*)&R1[e*64 + ((ks*4 + l4) ^ (e & 7))*8];
        #pragma unroll
        for (int ft = 0; ft < 8; ft++) {
            bf16x8 a = *(const bf16x8*)&W1t[(ft*16 + l15)*64 + (ks*4 + l4)*8];
            acc1[ft] = __builtin_amdgcn_mfma_f32_16x16x32_bf16(a, bfrag, acc1[ft], 0, 0, 0);
        }
    }
    __syncthreads();
    // write H1[e][f] = silu; f==114 -> 1.0 (GEMM2 bias slot); b64 stores
    #pragma unroll
    for (int ft = 0; ft < 8; ft++) {
        int e = row0 + l15;
        int f0 = ft*16 + l4*4;
        bf16x4 pk;
        #pragma unroll
        for (int r4 = 0; r4 < 4; r4++) {
            float hv = siluf(acc1[ft][r4]);
            if (f0 + r4 == EH) hv = 1.0f;
            pk[r4] = (bf16_t)hv;
        }
        *(bf16x4*)&R1[e*128 + ((f0 >> 3) ^ (e & 7))*8 + (f0 & 7)] = pk;
    }
    __syncthreads();

    // ---- GEMM2: M^T[f][e] = W2t[f][k] * H1^T[k][e] ----
    f32x4 acc2[4];
    #pragma unroll
    for (int ft = 0; ft < 4; ft++) acc2[ft] = (f32x4){0.f,0.f,0.f,0.f};
    #pragma unroll
    for (int ks = 0; ks < 4; ks++) {
        int e = row0 + l15;
        bf16x8 bfrag = *(const bf16x8*)&R1[e*128 + ((ks*4 + l4) ^ (e & 7))*8];
        #pragma unroll
        for (int ft = 0; ft < 4; ft++) {
            bf16x8 a = *(const bf16x8*)&W2t[(ft*16 + l15)*128 + (ks*4 + l4)*8];
            acc2[ft] = __builtin_amdgcn_mfma_f32_16x16x32_bf16(a, bfrag, acc2[ft], 0, 0, 0);
        }
    }
    __syncthreads();
    // write M[e][f] f32 (swizzled 16B granules), b128 stores
    #pragma unroll
    for (int ft = 0; ft < 4; ft++) {
        int e = row0 + l15;
        int f0 = ft*16 + l4*4;
        f32x4 v;
        #pragma unroll
        for (int r4 = 0; r4 < 4; r4++) v[r4] = siluf(acc2[ft][r4]);
        *(f32x4*)&Mf32[e*64 + (((f0 >> 2) ^ (e & 7)) << 2)] = v;
    }
    __syncthreads();

    // ---- m_i run-reduction (dst-sorted; 16-edge groups, 8 groups) ----
    {
        int col = t & 63;
        int gsw_base = col >> 2, cw = col & 3;
        int gb = (t >> 6) * 16;
        int cur = s_dst[gb];
        float run = 0.f;
        for (int i = 0; i < 16; i++) {
            int row = gb + i;
            int d = s_dst[row];
            float v = Mf32[row*64 + ((gsw_base ^ (row & 7)) << 2) + cw];
            if (d != cur) { atomicAdd(&m_i[(size_t)cur*64 + col], run); run = 0.f; cur = d; }
            run += v;
        }
        atomicAdd(&m_i[(size_t)cur*64 + col], run);
    }

    // ---- GEMM3 + run-reduced coor scatter (layer 0 only) ----
    if (COOR) {
        float csum = 0.f;
        #pragma unroll
        for (int half = 0; half < 2; half++) {
            f32x4 acc3[8];
            #pragma unroll
            for (int ft = 0; ft < 8; ft++) acc3[ft] = (f32x4){0.f,0.f,0.f,0.f};
            #pragma unroll
            for (int ks = 0; ks < 2; ks++) {
                int e = row0 + l15;
                int g0 = (ks*4 + l4) * 2;   // f32 16B-granule index (even)
                f32x4 lo = *(const f32x4*)&Mf32[e*64 + ((g0 ^ (e & 7)) << 2)];
                f32x4 hi = *(const f32x4*)&Mf32[e*64 + (((g0 + 1) ^ (e & 7)) << 2)];
                bf16x8 bfrag;
                #pragma unroll
                for (int j = 0; j < 4; j++) { bfrag[j] = (bf16_t)lo[j]; bfrag[j+4] = (bf16_t)hi[j]; }
                #pragma unroll
                for (int ft = 0; ft < 8; ft++) {
                    bf16x8 a = *(const bf16x8*)&CW1t[(half*128 + ft*16 + l15)*64 + (ks*4 + l4)*8];
                    acc3[ft] = __builtin_amdgcn_mfma_f32_16x16x32_bf16(a, bfrag, acc3[ft], 0, 0, 0);
                }
            }
            #pragma unroll
            for (int ft = 0; ft < 8; ft++) {
                int f0 = half*128 + ft*16 + l4*4;
                float4 c1 = *(const float4*)&cb1[f0];
                float4 w2 = *(const float4*)&cw2[f0];
                csum = fmaf(siluf(acc3[ft][0] + c1.x), w2.x, csum);
                csum = fmaf(siluf(acc3[ft][1] + c1.y), w2.y, csum);
                csum = fmaf(siluf(acc3[ft][2] + c1.z), w2.z, csum);
                csum = fmaf(siluf(acc3[ft][3] + c1.w), w2.w, csum);
            }
        }
        csum += __shfl_xor(csum, 16);
        csum += __shfl_xor(csum, 32);
        if (l < 16) {
            s_cacc[row0 + l] = csum + cb2[0];
        }
        __syncthreads();
        // run-reduce cdelta: one head thread per dst-run
        if (t < ETILE) {
            int d = s_dst[t];
            bool head = (t == 0) || (s_dst[t-1] != d);
            if (head) {
                float ax = 0.f, ay = 0.f, az = 0.f;
                int i = t;
                do {
                    float c = s_cacc[i];
                    ax = fmaf(c, s_rel[i*3+0], ax);
                    ay = fmaf(c, s_rel[i*3+1], ay);
                    az = fmaf(c, s_rel[i*3+2], az);
                    ++i;
                } while (i < ETILE && s_dst[i] == d);
                atomicAdd(&cdelta[d*3+0], ax);
                atomicAdd(&cdelta[d*3+1], ay);
                atomicAdd(&cdelta[d*3+2], az);
            }
        }
    }
}

// ---------------- node kernel: feats_out = feats + MLP([feats, m_i]) --------
template<int EMIT_BF16>
__global__ __launch_bounds__(256)
void node_kernel(const float* __restrict__ feats, const float* __restrict__ m_i,
                 const float* __restrict__ nw1, const float* __restrict__ nb1,
                 const float* __restrict__ nw2, const float* __restrict__ nb2,
                 float* __restrict__ fout, bf16_t* __restrict__ fbout)
{
    __shared__ float s_w1t[NH * NIN];
    __shared__ float s_b1[NH];
    __shared__ float s_w2[NH * EMB];
    __shared__ float s_b2[EMB];
    const int tid = threadIdx.x;
    for (int idx = tid; idx < NH * NIN; idx += 256) {
        int k = idx / NIN, i = idx - k * NIN;
        s_w1t[idx] = nw1[i * NH + k];
    }
    for (int idx = tid; idx < NH * EMB; idx += 256) s_w2[idx] = nw2[idx];
    if (tid < NH) s_b1[tid] = nb1[tid];
    if (tid < EMB) s_b2[tid] = nb2[tid];
    __syncthreads();

    int n = blockIdx.x * 256 + tid;
    if (n >= N_NODES) return;

    float in[NIN];
    const float4* fp = reinterpret_cast<const float4*>(feats + (size_t)n * EMB);
    #pragma unroll
    for (int q = 0; q < 6; q++) {
        float4 v = fp[q];
        in[q*4] = v.x; in[q*4+1] = v.y; in[q*4+2] = v.z; in[q*4+3] = v.w;
    }
    const float4* mp = reinterpret_cast<const float4*>(m_i + (size_t)n * MDIM);
    #pragma unroll
    for (int q = 0; q < 16; q++) {
        float4 v = mp[q];
        in[EMB+q*4] = v.x; in[EMB+q*4+1] = v.y; in[EMB+q*4+2] = v.z; in[EMB+q*4+3] = v.w;
    }
    float o[EMB];
    #pragma unroll
    for (int j = 0; j < EMB; j++) o[j] = in[j] + s_b2[j];
    for (int k = 0; k < NH; k++) {
        const float* w1 = &s_w1t[k * NIN];
        float a0 = 0.f, a1 = 0.f, a2 = 0.f, a3 = 0.f;
        #pragma unroll
        for (int i = 0; i < NIN; i += 4) {
            a0 = fmaf(in[i],   w1[i],   a0);
            a1 = fmaf(in[i+1], w1[i+1], a1);
            a2 = fmaf(in[i+2], w1[i+2], a2);
            a3 = fmaf(in[i+3], w1[i+3], a3);
        }
        float h = siluf(s_b1[k] + ((a0 + a1) + (a2 + a3)));
        const float* w2 = &s_w2[k * EMB];
        #pragma unroll
        for (int j = 0; j < EMB; j++) o[j] = fmaf(h, w2[j], o[j]);
    }
    float4* dst = reinterpret_cast<float4*>(fout + (size_t)n * EMB);
    #pragma unroll
    for (int q = 0; q < 6; q++) dst[q] = make_float4(o[q*4], o[q*4+1], o[q*4+2], o[q*4+3]);
    if (EMIT_BF16) {
        bf16x8* bdst = reinterpret_cast<bf16x8*>(fbout + (size_t)n * EMB);
        #pragma unroll
        for (int q = 0; q < 3; q++) {
            bf16x8 pk;
            #pragma unroll
            for (int j = 0; j < 8; j++) pk[j] = (bf16_t)o[q*8 + j];
            bdst[q] = pk;
        }
    }
}

// ---------------- coors update ----------------------------------------------
__global__ void coor_kernel(const float* __restrict__ pos, const float* __restrict__ cdelta,
                            float* __restrict__ out)
{
    int i = blockIdx.x * blockDim.x + threadIdx.x;
    if (i < N_NODES * 3) out[i] = pos[i] + cdelta[i];
}

// ---------------- fused MFMA FFNN: 512 thr / 8 waves (4 M-tiles x 2 N-halves)
__global__ __launch_bounds__(512, 4)
void ffnn_fused(const float* __restrict__ f0, const float* __restrict__ f1,
                const float* __restrict__ f2,
                const bf16_t* __restrict__ W0p, const bf16_t* __restrict__ W1p,
                const bf16_t* __restrict__ W2p,
                const float* __restrict__ b0, const float* __restrict__ b1,
                const float* __restrict__ b2,
                const int* __restrict__ batch, float* __restrict__ pooled)
{
    __shared__ __align__(16) bf16_t sH[NTILE * 256]; // 32KB
    __shared__ int s_batch[NTILE];
    const int t = threadIdx.x;
    const int w = t >> 6, l = t & 63;
    const int l15 = l & 15, q = l >> 4;
    const int mt = w & 3;          // M-tile (16 nodes)
    const int nh = w >> 2;         // N-half (8 nt of 16)
    const int mrow0 = mt * 16;
    const int n0 = blockIdx.x * NTILE;

    // ---- gather x = silu(concat(f0,f1,f2)) -> sH-as-[64][128] bf16 swz ----
    {
        int row = t >> 3, part = t & 7;
        int n = n0 + row;
        bool valid = n < N_NODES;
        if (part == 7) s_batch[row] = valid ? batch[n] : -1;
        #pragma unroll
        for (int gi = 0; gi < 2; gi++) {
            int g = part * 2 + gi;
            bf16x8 pk;
            #pragma unroll
            for (int j = 0; j < 8; j++) pk[j] = (bf16_t)0.f;
            if (valid && g < 9) {
                const float* sp = (g < 3) ? f0 + (size_t)n*EMB + 8*g
                                : (g < 6) ? f1 + (size_t)n*EMB + 8*(g-3)
                                          : f2 + (size_t)n*EMB + 8*(g-6);
                float4 a = ((const float4*)sp)[0], b = ((const float4*)sp)[1];
                pk[0]=(bf16_t)siluf(a.x); pk[1]=(bf16_t)siluf(a.y);
                pk[2]=(bf16_t)siluf(a.z); pk[3]=(bf16_t)siluf(a.w);
                pk[4]=(bf16_t)siluf(b.x); pk[5]=(bf16_t)siluf(b.y);
                pk[6]=(bf16_t)siluf(b.z); pk[7]=(bf16_t)siluf(b.w);
            }
            *(bf16x8*)&sH[row*128 + (g ^ (row & 7))*8] = pk;
        }
    }
    __syncthreads();

    // ---- L0: prefetch A to regs, then h = silu(x @ W0p + b0) ----
    bf16x8 a0[4];
    {
        int r = mrow0 + l15;
        #pragma unroll
        for (int ks = 0; ks < 4; ks++)
            a0[ks] = *(const bf16x8*)&sH[r*128 + ((ks*4 + q) ^ (r & 7))*8];
    }
    __syncthreads();   // all x reads done before sH is overwritten

    f32x4 acc[8];
    #pragma unroll
    for (int nt = 0; nt < 8; nt++) {
        float bv = b0[(nh*8 + nt)*16 + l15];
        acc[nt] = (f32x4){bv, bv, bv, bv};
    }
    #pragma unroll
    for (int ks = 0; ks < 4; ks++)
        #pragma unroll
        for (int nt = 0; nt < 8; nt++) {
            int n = (nh*8 + nt)*16 + l15;
            bf16x8 b = *(const bf16x8*)&W0p[n*128 + (ks*4 + q)*8];
            acc[nt] = __builtin_amdgcn_mfma_f32_16x16x32_bf16(a0[ks], b, acc[nt], 0, 0, 0);
        }
    #pragma unroll
    for (int nt = 0; nt < 8; nt++)
        #pragma unroll
        for (int r4 = 0; r4 < 4; r4++) {
            int row = mrow0 + q*4 + r4;
            int col = (nh*8 + nt)*16 + l15;
            sH[row*256 + ((col >> 3) ^ (row & 7))*8 + (col & 7)] = (bf16_t)siluf(acc[nt][r4]);
        }
    __syncthreads();

    // ---- L1 and L2: h = silu(h @ Wp + b) ----
    #pragma unroll
    for (int layer = 0; layer < 2; layer++) {
        const bf16_t* Wp = layer ? W2p : W1p;
        const float*  bb = layer ? b2  : b1;
        #pragma unroll
        for (int nt = 0; nt < 8; nt++) {
            float bv = bb[(nh*8 + nt)*16 + l15];
            acc[nt] = (f32x4){bv, bv, bv, bv};
        }
        for (int ks = 0; ks < 8; ks++) {
            int r = mrow0 + l15;
            bf16x8 a = *(const bf16x8*)&sH[r*256 + ((ks*4 + q) ^ (r & 7))*8];
            #pragma unroll
            for (int nt = 0; nt < 8; nt++) {
                int n = (nh*8 + nt)*16 + l15;
                bf16x8 b = *(const bf16x8*)&Wp[n*256 + (ks*4 + q)*8];
                acc[nt] = __builtin_amdgcn_mfma_f32_16x16x32_bf16(a, b, acc[nt], 0, 0, 0);
            }
        }
        __syncthreads();   // all h reads done before overwrite
        #pragma unroll
        for (int nt = 0; nt < 8; nt++)
            #pragma unroll
            for (int r4 = 0; r4 < 4; r4++) {
                int row = mrow0 + q*4 + r4;
                int col = (nh*8 + nt)*16 + l15;
                sH[row*256 + ((col >> 3) ^ (row & 7))*8 + (col & 7)] = (bf16_t)siluf(acc[nt][r4]);
            }
        __syncthreads();
    }

    // ---- fused pooling: 2 row-halves x 256 cols, batch-run reduction ----
    {
        int j = t & 255;
        int rh = t >> 8;
        int g = j >> 3, jo = j & 7;
        int cur = -1;
        float run = 0.f;
        for (int i = rh*32; i < rh*32 + 32; i++) {
            int bb = s_batch[i];
            if (bb != cur) {
                if (cur >= 0) atomicAdd(&pooled[cur * MLP + j], run);
                run = 0.f; cur = bb;
            }
            if (bb >= 0) run += (float)sH[i*256 + (g ^ (i & 7))*8 + jo];
        }
        if (cur >= 0) atomicAdd(&pooled[cur * MLP + j], run);
    }
}

// ---------------- final: sigmoid((pooled/cnt) @ fow + fob) ------------------
__global__ void final_kernel(const float* __restrict__ pooled, const float* __restrict__ cnt,
                             const float* __restrict__ fow, const float* __restrict__ fob,
                             float* __restrict__ out)
{
    int t = threadIdx.x;
    int bg = t >> 2, o = t & 3;
    float c = fmaxf(cnt[bg], 1.0f);
    float acc = 0.f;
    for (int i = 0; i < MLP; i++) acc = fmaf(pooled[bg * MLP + i], fow[i * 4 + o], acc);
    acc = acc / c + fob[o];
    out[t] = 1.0f / (1.0f + __expf(-acc));
}

extern "C" void kernel_launch(void* const* d_in, const int* in_sizes, int n_in,
                              void* d_out, int out_size, void* d_ws, size_t ws_size,
                              hipStream_t stream)
{
    const int*   z     = (const int*)  d_in[0];
    const float* pos   = (const float*)d_in[1];
    const int*   eidx  = (const int*)  d_in[2];
    const int*   batch = (const int*)  d_in[3];
    const float* embt  = (const float*)d_in[4];
    const float* embw  = (const float*)d_in[5];
    const float* embb  = (const float*)d_in[6];
    const float* ew1   = (const float*)d_in[7];
    const float* eb1   = (const float*)d_in[8];
    const float* ew2   = (const float*)d_in[9];
    const float* eb2   = (const float*)d_in[10];
    const float* cw1   = (const float*)d_in[11];
    const float* cb1   = (const float*)d_in[12];
    const float* cw2   = (const float*)d_in[13];
    const float* cb2   = (const float*)d_in[14];
    const float* nw1   = (const float*)d_in[15];
    const float* nb1   = (const float*)d_in[16];
    const float* nw2   = (const float*)d_in[17];
    const float* nb2   = (const float*)d_in[18];
    const float* f0w   = (const float*)d_in[19];
    const float* f0b   = (const float*)d_in[20];
    const float* f1w   = (const float*)d_in[21];
    const float* f1b   = (const float*)d_in[22];
    const float* f2w   = (const float*)d_in[23];
    const float* f2b   = (const float*)d_in[24];
    const float* fow   = (const float*)d_in[25];
    const float* fob   = (const float*)d_in[26];

    float* ws     = (float*)d_ws;
    float* f0     = ws;
    float* f1v    = f0 + (size_t)N_NODES * EMB;
    float* f2v    = f1v + (size_t)N_NODES * EMB;
    bf16_t* fb0   = (bf16_t*)(f2v + (size_t)N_NODES * EMB);
    bf16_t* fb1   = fb0 + (size_t)N_NODES * EMB;
    float* coorsA = (float*)(fb1 + (size_t)N_NODES * EMB);
    float* cdelta = coorsA + N_NODES * 3;
    float* m_i    = cdelta + N_NODES * 3;
    float* pooled = m_i + (size_t)N_NODES * MDIM;
    float* cnt    = pooled + N_GRAPHS * MLP;
    int*   deg    = (int*)(cnt + N_GRAPHS);
    int*   cursor = deg + N_NODES;
    int*   srcs_s = cursor + N_NODES;
    int*   dsts_s = srcs_s + N_EDGES;
    bf16_t* packw = (bf16_t*)(dsts_s + N_EDGES);
    bf16_t* W1t0  = packw;
    bf16_t* W1t1  = W1t0 + PK_W1;
    bf16_t* W2t0  = W1t1 + PK_W1;
    bf16_t* W2t1  = W2t0 + PK_W2;
    bf16_t* CW1t  = W2t1 + PK_W2;
    bf16_t* W0p   = CW1t + PK_CW;
    bf16_t* W1p   = W0p + PK_F0;
    bf16_t* W2p   = W1p + PK_FM;

    hipMemsetAsync(cdelta, 0, N_NODES * 3 * sizeof(float), stream);
    hipMemsetAsync(m_i, 0, (size_t)N_NODES * MDIM * sizeof(float), stream);
    hipMemsetAsync(pooled, 0, (N_GRAPHS * MLP + N_GRAPHS) * sizeof(float), stream);
    hipMemsetAsync(deg, 0, N_NODES * sizeof(int), stream);

    const int* e_src = eidx;
    const int* e_dst = eidx + N_EDGES;
    pack_kernel<<<(PK_TOT + 255) / 256, 256, 0, stream>>>(ew1, eb1, ew2, eb2, cw1,
                                                          f0w, f1w, f2w, packw);
    hist_kernel<<<(N_EDGES + 255) / 256, 256, 0, stream>>>(e_dst, deg);
    scan_kernel<<<1, 1024, 0, stream>>>(deg, cursor);
    scatter_kernel<<<(N_EDGES + 255) / 256, 256, 0, stream>>>(e_src, e_dst, cursor, srcs_s, dsts_s);

    embed_kernel<<<(N_NODES + 255) / 256, 256, 0, stream>>>(z, embt, embw, embb, batch, f0, fb0, cnt);

    const int EBLK = N_EDGES / ETILE; // 6250
    edge_mfma<1><<<EBLK, 512, 0, stream>>>(fb0, pos, srcs_s, dsts_s,
        W1t0, W2t0, CW1t, cb1, cw2, cb2, m_i, cdelta);
    node_kernel<1><<<(N_NODES + 255) / 256, 256, 0, stream>>>(f0, m_i, nw1, nb1, nw2, nb2, f1v, fb1);
    coor_kernel<<<(N_NODES * 3 + 255) / 256, 256, 0, stream>>>(pos, cdelta, coorsA);
    hipMemsetAsync(m_i, 0, (size_t)N_NODES * MDIM * sizeof(float), stream);
    edge_mfma<0><<<EBLK, 512, 0, stream>>>(fb1, coorsA, srcs_s, dsts_s,
        W1t1, W2t1, CW1t, cb1, cw2, cb2, m_i, nullptr);
    node_kernel<0><<<(N_NODES + 255) / 256, 256, 0, stream>>>(f1v, m_i,
        nw1 + NIN * NH, nb1 + NH, nw2 + NH * EMB, nb2 + EMB, f2v, nullptr);

    const int FBLK = (N_NODES + NTILE - 1) / NTILE;
    ffnn_fused<<<FBLK, 512, 0, stream>>>(f0, f1v, f2v, W0p, W1p, W2p,
                                         f0b, f1b, f2b, batch, pooled);

    final_kernel<<<1, 256, 0, stream>>>(pooled, cnt, fow, fob, (float*)d_out);
}

// Round 7
// 972.355 us; speedup vs baseline: 1.2925x; 1.2925x over previous
//
#include <hip/hip_runtime.h>
#include <hip/hip_bf16.h>

#define N_NODES  50000
#define N_EDGES  800000
#define N_GRAPHS 64
#define EMB      24
#define MDIM     64
#define EDGE_IN  57
#define EH       114   // EDGE_IN*2
#define CH       256   // M_DIM*4
#define NIN      88    // EMB+MDIM
#define NH       48    // EMB*2
#define MLP      256
#define ETILE    128
#define NTILE    64

typedef __bf16 bf16_t;
typedef __bf16 bf16x8 __attribute__((ext_vector_type(8)));
typedef __bf16 bf16x4 __attribute__((ext_vector_type(4)));
typedef float  f32x4  __attribute__((ext_vector_type(4)));

__device__ __forceinline__ float siluf(float x) {
    return x * __builtin_amdgcn_rcpf(1.0f + __expf(-x));
}

// ---------------- embedding: feats0 = emb_table[z] @ emb_w + emb_b ----------
__global__ void embed_kernel(const int* __restrict__ z, const float* __restrict__ table,
                             const float* __restrict__ w, const float* __restrict__ b,
                             const int* __restrict__ batch, float* __restrict__ f0,
                             bf16_t* __restrict__ fb0, float* __restrict__ cnt)
{
    int n = blockIdx.x * blockDim.x + threadIdx.x;
    if (n >= N_NODES) return;
    float r[EMB];
    const float4* tr = reinterpret_cast<const float4*>(table + z[n] * EMB);
    #pragma unroll
    for (int q = 0; q < 6; q++) {
        float4 v = tr[q];
        r[q*4] = v.x; r[q*4+1] = v.y; r[q*4+2] = v.z; r[q*4+3] = v.w;
    }
    float o[EMB];
    #pragma unroll
    for (int j = 0; j < EMB; j++) o[j] = b[j];
    #pragma unroll
    for (int i = 0; i < EMB; i++) {
        #pragma unroll
        for (int j = 0; j < EMB; j++) o[j] = fmaf(r[i], w[i*EMB + j], o[j]);
    }
    float4* dst = reinterpret_cast<float4*>(f0 + (size_t)n * EMB);
    #pragma unroll
    for (int q = 0; q < 6; q++) dst[q] = make_float4(o[q*4], o[q*4+1], o[q*4+2], o[q*4+3]);
    bf16x8* bdst = reinterpret_cast<bf16x8*>(fb0 + (size_t)n * EMB);
    #pragma unroll
    for (int q = 0; q < 3; q++) {
        bf16x8 pk;
        #pragma unroll
        for (int j = 0; j < 8; j++) pk[j] = (bf16_t)o[q*8 + j];
        bdst[q] = pk;
    }
    atomicAdd(&cnt[batch[n]], 1.0f);
}

// ---------------- weight pre-pack to bf16 MFMA layout (A-operand [n][k]) ----
#define PK_W1   (128*64)
#define PK_W2   (64*128)
#define PK_CW   (256*64)
#define PK_F0   (256*128)
#define PK_FM   (256*256)
#define PK_TOT  (2*PK_W1 + 2*PK_W2 + PK_CW + PK_F0 + 2*PK_FM)
__global__ void pack_kernel(const float* __restrict__ ew1, const float* __restrict__ eb1,
                            const float* __restrict__ ew2, const float* __restrict__ eb2,
                            const float* __restrict__ cw1, const float* __restrict__ f0w,
                            const float* __restrict__ f1w, const float* __restrict__ f2w,
                            bf16_t* __restrict__ pw)
{
    int idx = blockIdx.x * blockDim.x + threadIdx.x;
    if (idx >= PK_TOT) return;
    float v = 0.0f;
    if (idx < 2 * PK_W1) {
        int l = idx / PK_W1, r = idx - l * PK_W1;
        int n = r >> 6, k = r & 63;
        if (n < EH && k < EDGE_IN)       v = ew1[(l * EDGE_IN + k) * EH + n];
        else if (n < EH && k == EDGE_IN) v = eb1[l * EH + n];
    } else if (idx < 2 * PK_W1 + 2 * PK_W2) {
        int r0 = idx - 2 * PK_W1;
        int l = r0 / PK_W2, r = r0 - l * PK_W2;
        int n = r >> 7, k = r & 127;
        if (k < EH)       v = ew2[(l * EH + k) * MDIM + n];
        else if (k == EH) v = eb2[l * MDIM + n];
    } else if (idx < 2 * PK_W1 + 2 * PK_W2 + PK_CW) {
        int r = idx - (2 * PK_W1 + 2 * PK_W2);
        int n = r >> 6, k = r & 63;
        v = cw1[k * CH + n];
    } else if (idx < 2 * PK_W1 + 2 * PK_W2 + PK_CW + PK_F0) {
        int r = idx - (2 * PK_W1 + 2 * PK_W2 + PK_CW);
        int n = r >> 7, k = r & 127;
        if (k < 72) v = f0w[k * MLP + n];
    } else {
        int r0 = idx - (2 * PK_W1 + 2 * PK_W2 + PK_CW + PK_F0);
        int l = r0 / PK_FM, r = r0 - l * PK_FM;
        int n = r >> 8, k = r & 255;
        v = (l == 0) ? f1w[k * MLP + n] : f2w[k * MLP + n];
    }
    pw[idx] = (bf16_t)v;
}

// ---------------- CSR build --------------------------------------------------
__global__ void hist_kernel(const int* __restrict__ dst, int* __restrict__ deg)
{
    int e = blockIdx.x * blockDim.x + threadIdx.x;
    if (e < N_EDGES) atomicAdd(&deg[dst[e]], 1);
}

__global__ __launch_bounds__(1024)
void scan_kernel(const int* __restrict__ deg, int* __restrict__ cursor)
{
    __shared__ int part[1024];
    int t = threadIdx.x;
    const int PER = 49;
    int base = t * PER;
    int s = 0;
    for (int i = 0; i < PER; i++) {
        int p = base + i;
        if (p < N_NODES) s += deg[p];
    }
    part[t] = s;
    __syncthreads();
    for (int off = 1; off < 1024; off <<= 1) {
        int add = (t >= off) ? part[t - off] : 0;
        __syncthreads();
        part[t] += add;
        __syncthreads();
    }
    int run = (t > 0) ? part[t - 1] : 0;
    for (int i = 0; i < PER; i++) {
        int p = base + i;
        if (p < N_NODES) { cursor[p] = run; run += deg[p]; }
    }
}

__global__ void scatter_kernel(const int* __restrict__ src, const int* __restrict__ dst,
                               int* __restrict__ cursor, int* __restrict__ srcs_s,
                               int* __restrict__ dsts_s)
{
    int e = blockIdx.x * blockDim.x + threadIdx.x;
    if (e >= N_EDGES) return;
    int d = dst[e];
    int pos = atomicAdd(&cursor[d], 1);
    srcs_s[pos] = src[e];
    dsts_s[pos] = d;
}

// ---------------- fused MFMA edge kernel: WAVE-AUTONOMOUS, ZERO BARRIERS ----
// 256 thr / 4 waves / 128 edges. Each wave owns a 32-edge stripe and an 8KB
// LDS slab (union: Ein bf16 [32][64] -> H1 bf16 [32][128] -> M f32 [32][64]).
// All LDS traffic is wave-private (gather, GEMMs, m_i reduce, cdelta reduce)
// -> no __syncthreads anywhere; waves free-run past each other.
// A = weights [n][k] (global, L2-hot); B = data^T (LDS); D = out^T (lane holds
// 4 consecutive features of one edge). Swizzle: 16B granule g ^ (row&7).
template<int COOR>
__global__ __launch_bounds__(256, 4)
void edge_mfma(const bf16_t* __restrict__ fb, const float* __restrict__ coors,
               const int* __restrict__ srcs_s, const int* __restrict__ dsts_s,
               const bf16_t* __restrict__ W1t, const bf16_t* __restrict__ W2t,
               const bf16_t* __restrict__ CW1t, const float* __restrict__ cb1,
               const float* __restrict__ cw2, const float* __restrict__ cb2,
               float* __restrict__ m_i, float* __restrict__ cdelta)
{
    __shared__ __align__(16) char R1raw[4 * 8192];        // 4 slabs x 8KB
    __shared__ float s_rel[COOR ? ETILE * 3 : 4];
    __shared__ float s_cacc[COOR ? ETILE : 4];
    __shared__ int   s_dst[ETILE];

    const int t = threadIdx.x;
    const int w = t >> 6;
    const int l = t & 63;
    const int row0 = w * 32;          // wave's global stripe base
    const int ebase = blockIdx.x * ETILE;
    const int l15 = l & 15, l4 = l >> 4;
    bf16_t* slab16 = (bf16_t*)(R1raw + w * 8192);
    float*  slab32 = (float*) (R1raw + w * 8192);

    // ---- gather: 2 threads per edge (own stripe only) ----
    {
        int e_loc = t >> 1, half = t & 1;   // e_loc in [row0, row0+32)
        int e_l = e_loc & 31;
        int e = ebase + e_loc;
        int s = srcs_s[e], d = dsts_s[e];
        if (half == 0) {
            s_dst[e_loc] = d;
            const bf16x8* fp = reinterpret_cast<const bf16x8*>(fb + (size_t)d * EMB);
            #pragma unroll
            for (int g = 0; g < 3; g++)
                *(bf16x8*)&slab16[e_l*64 + (g ^ (e_l & 7))*8] = fp[g];
        } else {
            const bf16x8* fp = reinterpret_cast<const bf16x8*>(fb + (size_t)s * EMB);
            #pragma unroll
            for (int g = 0; g < 3; g++)
                *(bf16x8*)&slab16[e_l*64 + ((g + 3) ^ (e_l & 7))*8] = fp[g];
            float rx = coors[s*3+0] - coors[d*3+0];
            float ry = coors[s*3+1] - coors[d*3+1];
            float rz = coors[s*3+2] - coors[d*3+2];
            float d2 = rx*rx + ry*ry + rz*rz;
            if (COOR) { s_rel[e_loc*3+0] = rx; s_rel[e_loc*3+1] = ry; s_rel[e_loc*3+2] = rz; }
            bf16x8 p6, p7;
            p6[0]=(bf16_t)__sinf(d2);        p6[1]=(bf16_t)__sinf(d2*0.5f);
            p6[2]=(bf16_t)__sinf(d2*0.25f);  p6[3]=(bf16_t)__sinf(d2*0.125f);
            p6[4]=(bf16_t)__cosf(d2);        p6[5]=(bf16_t)__cosf(d2*0.5f);
            p6[6]=(bf16_t)__cosf(d2*0.25f);  p6[7]=(bf16_t)__cosf(d2*0.125f);
            p7[0]=(bf16_t)d2; p7[1]=(bf16_t)1.0f;
            p7[2]=(bf16_t)0.f; p7[3]=(bf16_t)0.f; p7[4]=(bf16_t)0.f;
            p7[5]=(bf16_t)0.f; p7[6]=(bf16_t)0.f; p7[7]=(bf16_t)0.f;
            *(bf16x8*)&slab16[e_l*64 + (6 ^ (e_l & 7))*8] = p6;
            *(bf16x8*)&slab16[e_l*64 + (7 ^ (e_l & 7))*8] = p7;
        }
    }
    // no barrier: all subsequent reads are this wave's own slab rows

    // ---- GEMM1: H1^T[f][e] = W1t[f][k] * Ein^T[k][e] ----
    f32x4 acc1[2][8];
    #pragma unroll
    for (int et = 0; et < 2; et++)
        #pragma unroll
        for (int ft = 0; ft < 8; ft++) acc1[et][ft] = (f32x4){0.f,0.f,0.f,0.f};
    #pragma unroll
    for (int ks = 0; ks < 2; ks++) {
        bf16x8 bfrag[2];
        #pragma unroll
        for (int et = 0; et < 2; et++) {
            int e_l = et*16 + l15;
            bfrag[et] = *(const bf16x8*)&slab16[e_l*64 + ((ks*4 + l4) ^ (e_l & 7))*8];
        }
        #pragma unroll
        for (int ft = 0; ft < 8; ft++) {
            bf16x8 a = *(const bf16x8*)&W1t[(ft*16 + l15)*64 + (ks*4 + l4)*8];
            acc1[0][ft] = __builtin_amdgcn_mfma_f32_16x16x32_bf16(a, bfrag[0], acc1[0][ft], 0, 0, 0);
            acc1[1][ft] = __builtin_amdgcn_mfma_f32_16x16x32_bf16(a, bfrag[1], acc1[1][ft], 0, 0, 0);
        }
    }
    // write H1[e][f] = silu; f==114 -> 1.0 (GEMM2 bias slot); b64 stores
    #pragma unroll
    for (int et = 0; et < 2; et++)
        #pragma unroll
        for (int ft = 0; ft < 8; ft++) {
            int e_l = et*16 + l15;
            int f0 = ft*16 + l4*4;
            bf16x4 pk;
            #pragma unroll
            for (int r4 = 0; r4 < 4; r4++) {
                float hv = siluf(acc1[et][ft][r4]);
                if (f0 + r4 == EH) hv = 1.0f;
                pk[r4] = (bf16_t)hv;
            }
            *(bf16x4*)&slab16[e_l*128 + ((f0 >> 3) ^ (e_l & 7))*8 + (f0 & 7)] = pk;
        }

    // ---- GEMM2: M^T[f][e] = W2t[f][k] * H1^T[k][e] ----
    f32x4 acc2[2][4];
    #pragma unroll
    for (int et = 0; et < 2; et++)
        #pragma unroll
        for (int ft = 0; ft < 4; ft++) acc2[et][ft] = (f32x4){0.f,0.f,0.f,0.f};
    #pragma unroll
    for (int ks = 0; ks < 4; ks++) {
        bf16x8 bfrag[2];
        #pragma unroll
        for (int et = 0; et < 2; et++) {
            int e_l = et*16 + l15;
            bfrag[et] = *(const bf16x8*)&slab16[e_l*128 + ((ks*4 + l4) ^ (e_l & 7))*8];
        }
        #pragma unroll
        for (int ft = 0; ft < 4; ft++) {
            bf16x8 a = *(const bf16x8*)&W2t[(ft*16 + l15)*128 + (ks*4 + l4)*8];
            acc2[0][ft] = __builtin_amdgcn_mfma_f32_16x16x32_bf16(a, bfrag[0], acc2[0][ft], 0, 0, 0);
            acc2[1][ft] = __builtin_amdgcn_mfma_f32_16x16x32_bf16(a, bfrag[1], acc2[1][ft], 0, 0, 0);
        }
    }
    // write M[e][f] f32 (swizzled 16B granules), b128 stores
    #pragma unroll
    for (int et = 0; et < 2; et++)
        #pragma unroll
        for (int ft = 0; ft < 4; ft++) {
            int e_l = et*16 + l15;
            int f0 = ft*16 + l4*4;
            f32x4 v;
            #pragma unroll
            for (int r4 = 0; r4 < 4; r4++) v[r4] = siluf(acc2[et][ft][r4]);
            *(f32x4*)&slab32[e_l*64 + (((f0 >> 2) ^ (e_l & 7)) << 2)] = v;
        }

    // ---- m_i run-reduction (dst-sorted; wave's own 32-edge stripe) ----
    {
        int col = l;
        int gsw_base = col >> 2, cw = col & 3;
        int cur = s_dst[row0];
        float run = 0.f;
        for (int i = 0; i < 32; i++) {
            int d = s_dst[row0 + i];
            float v = slab32[i*64 + ((gsw_base ^ (i & 7)) << 2) + cw];
            if (d != cur) { atomicAdd(&m_i[(size_t)cur*64 + col], run); run = 0.f; cur = d; }
            run += v;
        }
        atomicAdd(&m_i[(size_t)cur*64 + col], run);
    }

    // ---- GEMM3 + per-wave run-reduced coor scatter (layer 0 only) ----
    if (COOR) {
        float csum0 = 0.f, csum1 = 0.f;
        #pragma unroll
        for (int half = 0; half < 2; half++) {
            f32x4 acc3[2][8];
            #pragma unroll
            for (int et = 0; et < 2; et++)
                #pragma unroll
                for (int ft = 0; ft < 8; ft++) acc3[et][ft] = (f32x4){0.f,0.f,0.f,0.f};
            #pragma unroll
            for (int ks = 0; ks < 2; ks++) {
                bf16x8 bfrag[2];
                #pragma unroll
                for (int et = 0; et < 2; et++) {
                    int e_l = et*16 + l15;
                    int g0 = (ks*4 + l4) * 2;   // f32 16B-granule index (even)
                    f32x4 lo = *(const f32x4*)&slab32[e_l*64 + ((g0 ^ (e_l & 7)) << 2)];
                    f32x4 hi = *(const f32x4*)&slab32[e_l*64 + (((g0 + 1) ^ (e_l & 7)) << 2)];
                    bf16x8 bk;
                    #pragma unroll
                    for (int j = 0; j < 4; j++) { bk[j] = (bf16_t)lo[j]; bk[j+4] = (bf16_t)hi[j]; }
                    bfrag[et] = bk;
                }
                #pragma unroll
                for (int ft = 0; ft < 8; ft++) {
                    bf16x8 a = *(const bf16x8*)&CW1t[(half*128 + ft*16 + l15)*64 + (ks*4 + l4)*8];
                    acc3[0][ft] = __builtin_amdgcn_mfma_f32_16x16x32_bf16(a, bfrag[0], acc3[0][ft], 0, 0, 0);
                    acc3[1][ft] = __builtin_amdgcn_mfma_f32_16x16x32_bf16(a, bfrag[1], acc3[1][ft], 0, 0, 0);
                }
            }
            #pragma unroll
            for (int ft = 0; ft < 8; ft++) {
                int f0 = half*128 + ft*16 + l4*4;
                float4 c1 = *(const float4*)&cb1[f0];
                float4 w2 = *(const float4*)&cw2[f0];
                csum0 = fmaf(siluf(acc3[0][ft][0] + c1.x), w2.x, csum0);
                csum0 = fmaf(siluf(acc3[0][ft][1] + c1.y), w2.y, csum0);
                csum0 = fmaf(siluf(acc3[0][ft][2] + c1.z), w2.z, csum0);
                csum0 = fmaf(siluf(acc3[0][ft][3] + c1.w), w2.w, csum0);
                csum1 = fmaf(siluf(acc3[1][ft][0] + c1.x), w2.x, csum1);
                csum1 = fmaf(siluf(acc3[1][ft][1] + c1.y), w2.y, csum1);
                csum1 = fmaf(siluf(acc3[1][ft][2] + c1.z), w2.z, csum1);
                csum1 = fmaf(siluf(acc3[1][ft][3] + c1.w), w2.w, csum1);
            }
        }
        // reduce over the 16-lane feature groups -> every lane holds totals
        csum0 += __shfl_xor(csum0, 16);
        csum0 += __shfl_xor(csum0, 32);
        csum1 += __shfl_xor(csum1, 16);
        csum1 += __shfl_xor(csum1, 32);
        float cb2v = cb2[0];
        if (l < 32) {
            // lane l owns edge row0+l: l<16 -> csum0 (et=0), l>=16 -> csum1
            s_cacc[row0 + l] = ((l & 16) ? csum1 : csum0) + cb2v;
        }
        // per-wave run-reduce over own 32 edges (runs split at stripe edges
        // just produce one extra atomic; atomics sum correctly)
        if (l < 32) {
            int row = row0 + l;
            int d = s_dst[row];
            bool head = (l == 0) || (s_dst[row - 1] != d);
            if (head) {
                float ax = 0.f, ay = 0.f, az = 0.f;
                int i = l;
                do {
                    int r = row0 + i;
                    float c = s_cacc[r];
                    ax = fmaf(c, s_rel[r*3+0], ax);
                    ay = fmaf(c, s_rel[r*3+1], ay);
                    az = fmaf(c, s_rel[r*3+2], az);
                    ++i;
                } while (i < 32 && s_dst[row0 + i] == d);
                atomicAdd(&cdelta[d*3+0], ax);
                atomicAdd(&cdelta[d*3+1], ay);
                atomicAdd(&cdelta[d*3+2], az);
            }
        }
    }
}

// ---------------- node kernel: feats_out = feats + MLP([feats, m_i]) --------
template<int EMIT_BF16>
__global__ __launch_bounds__(256)
void node_kernel(const float* __restrict__ feats, const float* __restrict__ m_i,
                 const float* __restrict__ nw1, const float* __restrict__ nb1,
                 const float* __restrict__ nw2, const float* __restrict__ nb2,
                 float* __restrict__ fout, bf16_t* __restrict__ fbout)
{
    __shared__ float s_w1t[NH * NIN];
    __shared__ float s_b1[NH];
    __shared__ float s_w2[NH * EMB];
    __shared__ float s_b2[EMB];
    const int tid = threadIdx.x;
    for (int idx = tid; idx < NH * NIN; idx += 256) {
        int k = idx / NIN, i = idx - k * NIN;
        s_w1t[idx] = nw1[i * NH + k];
    }
    for (int idx = tid; idx < NH * EMB; idx += 256) s_w2[idx] = nw2[idx];
    if (tid < NH) s_b1[tid] = nb1[tid];
    if (tid < EMB) s_b2[tid] = nb2[tid];
    __syncthreads();

    int n = blockIdx.x * 256 + tid;
    if (n >= N_NODES) return;

    float in[NIN];
    const float4* fp = reinterpret_cast<const float4*>(feats + (size_t)n * EMB);
    #pragma unroll
    for (int q = 0; q < 6; q++) {
        float4 v = fp[q];
        in[q*4] = v.x; in[q*4+1] = v.y; in[q*4+2] = v.z; in[q*4+3] = v.w;
    }
    const float4* mp = reinterpret_cast<const float4*>(m_i + (size_t)n * MDIM);
    #pragma unroll
    for (int q = 0; q < 16; q++) {
        float4 v = mp[q];
        in[EMB+q*4] = v.x; in[EMB+q*4+1] = v.y; in[EMB+q*4+2] = v.z; in[EMB+q*4+3] = v.w;
    }
    float o[EMB];
    #pragma unroll
    for (int j = 0; j < EMB; j++) o[j] = in[j] + s_b2[j];
    for (int k = 0; k < NH; k++) {
        const float* w1 = &s_w1t[k * NIN];
        float a0 = 0.f, a1 = 0.f, a2 = 0.f, a3 = 0.f;
        #pragma unroll
        for (int i = 0; i < NIN; i += 4) {
            a0 = fmaf(in[i],   w1[i],   a0);
            a1 = fmaf(in[i+1], w1[i+1], a1);
            a2 = fmaf(in[i+2], w1[i+2], a2);
            a3 = fmaf(in[i+3], w1[i+3], a3);
        }
        float h = siluf(s_b1[k] + ((a0 + a1) + (a2 + a3)));
        const float* w2 = &s_w2[k * EMB];
        #pragma unroll
        for (int j = 0; j < EMB; j++) o[j] = fmaf(h, w2[j], o[j]);
    }
    float4* dst = reinterpret_cast<float4*>(fout + (size_t)n * EMB);
    #pragma unroll
    for (int q = 0; q < 6; q++) dst[q] = make_float4(o[q*4], o[q*4+1], o[q*4+2], o[q*4+3]);
    if (EMIT_BF16) {
        bf16x8* bdst = reinterpret_cast<bf16x8*>(fbout + (size_t)n * EMB);
        #pragma unroll
        for (int q = 0; q < 3; q++) {
            bf16x8 pk;
            #pragma unroll
            for (int j = 0; j < 8; j++) pk[j] = (bf16_t)o[q*8 + j];
            bdst[q] = pk;
        }
    }
}

// ---------------- coors update ----------------------------------------------
__global__ void coor_kernel(const float* __restrict__ pos, const float* __restrict__ cdelta,
                            float* __restrict__ out)
{
    int i = blockIdx.x * blockDim.x + threadIdx.x;
    if (i < N_NODES * 3) out[i] = pos[i] + cdelta[i];
}

// ---------------- fused MFMA FFNN: 512 thr / 8 waves (4 M-tiles x 2 N-halves)
__global__ __launch_bounds__(512, 4)
void ffnn_fused(const float* __restrict__ f0, const float* __restrict__ f1,
                const float* __restrict__ f2,
                const bf16_t* __restrict__ W0p, const bf16_t* __restrict__ W1p,
                const bf16_t* __restrict__ W2p,
                const float* __restrict__ b0, const float* __restrict__ b1,
                const float* __restrict__ b2,
                const int* __restrict__ batch, float* __restrict__ pooled)
{
    __shared__ __align__(16) bf16_t sH[NTILE * 256]; // 32KB
    __shared__ int s_batch[NTILE];
    const int t = threadIdx.x;
    const int w = t >> 6, l = t & 63;
    const int l15 = l & 15, q = l >> 4;
    const int mt = w & 3;          // M-tile (16 nodes)
    const int nh = w >> 2;         // N-half (8 nt of 16)
    const int mrow0 = mt * 16;
    const int n0 = blockIdx.x * NTILE;

    // ---- gather x = silu(concat(f0,f1,f2)) -> sH-as-[64][128] bf16 swz ----
    {
        int row = t >> 3, part = t & 7;
        int n = n0 + row;
        bool valid = n < N_NODES;
        if (part == 7) s_batch[row] = valid ? batch[n] : -1;
        #pragma unroll
        for (int gi = 0; gi < 2; gi++) {
            int g = part * 2 + gi;
            bf16x8 pk;
            #pragma unroll
            for (int j = 0; j < 8; j++) pk[j] = (bf16_t)0.f;
            if (valid && g < 9) {
                const float* sp = (g < 3) ? f0 + (size_t)n*EMB + 8*g
                                : (g < 6) ? f1 + (size_t)n*EMB + 8*(g-3)
                                          : f2 + (size_t)n*EMB + 8*(g-6);
                float4 a = ((const float4*)sp)[0], b = ((const float4*)sp)[1];
                pk[0]=(bf16_t)siluf(a.x); pk[1]=(bf16_t)siluf(a.y);
                pk[2]=(bf16_t)siluf(a.z); pk[3]=(bf16_t)siluf(a.w);
                pk[4]=(bf16_t)siluf(b.x); pk[5]=(bf16_t)siluf(b.y);
                pk[6]=(bf16_t)siluf(b.z); pk[7]=(bf16_t)siluf(b.w);
            }
            *(bf16x8*)&sH[row*128 + (g ^ (row & 7))*8] = pk;
        }
    }
    __syncthreads();

    // ---- L0: prefetch A to regs, then h = silu(x @ W0p + b0) ----
    bf16x8 a0[4];
    {
        int r = mrow0 + l15;
        #pragma unroll
        for (int ks = 0; ks < 4; ks++)
            a0[ks] = *(const bf16x8*)&sH[r*128 + ((ks*4 + q) ^ (r & 7))*8];
    }
    __syncthreads();   // all x reads done before sH is overwritten

    f32x4 acc[8];
    #pragma unroll
    for (int nt = 0; nt < 8; nt++) {
        float bv = b0[(nh*8 + nt)*16 + l15];
        acc[nt] = (f32x4){bv, bv, bv, bv};
    }
    #pragma unroll
    for (int ks = 0; ks < 4; ks++)
        #pragma unroll
        for (int nt = 0; nt < 8; nt++) {
            int n = (nh*8 + nt)*16 + l15;
            bf16x8 b = *(const bf16x8*)&W0p[n*128 + (ks*4 + q)*8];
            acc[nt] = __builtin_amdgcn_mfma_f32_16x16x32_bf16(a0[ks], b, acc[nt], 0, 0, 0);
        }
    #pragma unroll
    for (int nt = 0; nt < 8; nt++)
        #pragma unroll
        for (int r4 = 0; r4 < 4; r4++) {
            int row = mrow0 + q*4 + r4;
            int col = (nh*8 + nt)*16 + l15;
            sH[row*256 + ((col >> 3) ^ (row & 7))*8 + (col & 7)] = (bf16_t)siluf(acc[nt][r4]);
        }
    __syncthreads();

    // ---- L1 and L2: h = silu(h @ Wp + b) ----
    #pragma unroll
    for (int layer = 0; layer < 2; layer++) {
        const bf16_t* Wp = layer ? W2p : W1p;
        const float*  bb = layer ? b2  : b1;
        #pragma unroll
        for (int nt = 0; nt < 8; nt++) {
            float bv = bb[(nh*8 + nt)*16 + l15];
            acc[nt] = (f32x4){bv, bv, bv, bv};
        }
        for (int ks = 0; ks < 8; ks++) {
            int r = mrow0 + l15;
            bf16x8 a = *(const bf16x8*)&sH[r*256 + ((ks*4 + q) ^ (r & 7))*8];
            #pragma unroll
            for (int nt = 0; nt < 8; nt++) {
                int n = (nh*8 + nt)*16 + l15;
                bf16x8 b = *(const bf16x8*)&Wp[n*256 + (ks*4 + q)*8];
                acc[nt] = __builtin_amdgcn_mfma_f32_16x16x32_bf16(a, b, acc[nt], 0, 0, 0);
            }
        }
        __syncthreads();   // all h reads done before overwrite
        #pragma unroll
        for (int nt = 0; nt < 8; nt++)
            #pragma unroll
            for (int r4 = 0; r4 < 4; r4++) {
                int row = mrow0 + q*4 + r4;
                int col = (nh*8 + nt)*16 + l15;
                sH[row*256 + ((col >> 3) ^ (row & 7))*8 + (col & 7)] = (bf16_t)siluf(acc[nt][r4]);
            }
        __syncthreads();
    }

    // ---- fused pooling: 2 row-halves x 256 cols, batch-run reduction ----
    {
        int j = t & 255;
        int rh = t >> 8;
        int g = j >> 3, jo = j & 7;
        int cur = -1;
        float run = 0.f;
        for (int i = rh*32; i < rh*32 + 32; i++) {
            int bb = s_batch[i];
            if (bb != cur) {
                if (cur >= 0) atomicAdd(&pooled[cur * MLP + j], run);
                run = 0.f; cur = bb;
            }
            if (bb >= 0) run += (float)sH[i*256 + (g ^ (i & 7))*8 + jo];
        }
        if (cur >= 0) atomicAdd(&pooled[cur * MLP + j], run);
    }
}

// ---------------- final: sigmoid((pooled/cnt) @ fow + fob) ------------------
__global__ void final_kernel(const float* __restrict__ pooled, const float* __restrict__ cnt,
                             const float* __restrict__ fow, const float* __restrict__ fob,
                             float* __restrict__ out)
{
    int t = threadIdx.x;
    int bg = t >> 2, o = t & 3;
    float c = fmaxf(cnt[bg], 1.0f);
    float acc = 0.f;
    for (int i = 0; i < MLP; i++) acc = fmaf(pooled[bg * MLP + i], fow[i * 4 + o], acc);
    acc = acc / c + fob[o];
    out[t] = 1.0f / (1.0f + __expf(-acc));
}

extern "C" void kernel_launch(void* const* d_in, const int* in_sizes, int n_in,
                              void* d_out, int out_size, void* d_ws, size_t ws_size,
                              hipStream_t stream)
{
    const int*   z     = (const int*)  d_in[0];
    const float* pos   = (const float*)d_in[1];
    const int*   eidx  = (const int*)  d_in[2];
    const int*   batch = (const int*)  d_in[3];
    const float* embt  = (const float*)d_in[4];
    const float* embw  = (const float*)d_in[5];
    const float* embb  = (const float*)d_in[6];
    const float* ew1   = (const float*)d_in[7];
    const float* eb1   = (const float*)d_in[8];
    const float* ew2   = (const float*)d_in[9];
    const float* eb2   = (const float*)d_in[10];
    const float* cw1   = (const float*)d_in[11];
    const float* cb1   = (const float*)d_in[12];
    const float* cw2   = (const float*)d_in[13];
    const float* cb2   = (const float*)d_in[14];
    const float* nw1   = (const float*)d_in[15];
    const float* nb1   = (const float*)d_in[16];
    const float* nw2   = (const float*)d_in[17];
    const float* nb2   = (const float*)d_in[18];
    const float* f0w   = (const float*)d_in[19];
    const float* f0b   = (const float*)d_in[20];
    const float* f1w   = (const float*)d_in[21];
    const float* f1b   = (const float*)d_in[22];
    const float* f2w   = (const float*)d_in[23];
    const float* f2b   = (const float*)d_in[24];
    const float* fow   = (const float*)d_in[25];
    const float* fob   = (const float*)d_in[26];

    float* ws     = (float*)d_ws;
    float* f0     = ws;
    float* f1v    = f0 + (size_t)N_NODES * EMB;
    float* f2v    = f1v + (size_t)N_NODES * EMB;
    bf16_t* fb0   = (bf16_t*)(f2v + (size_t)N_NODES * EMB);
    bf16_t* fb1   = fb0 + (size_t)N_NODES * EMB;
    float* coorsA = (float*)(fb1 + (size_t)N_NODES * EMB);
    float* cdelta = coorsA + N_NODES * 3;
    float* m_i    = cdelta + N_NODES * 3;
    float* pooled = m_i + (size_t)N_NODES * MDIM;
    float* cnt    = pooled + N_GRAPHS * MLP;
    int*   deg    = (int*)(cnt + N_GRAPHS);
    int*   cursor = deg + N_NODES;
    int*   srcs_s = cursor + N_NODES;
    int*   dsts_s = srcs_s + N_EDGES;
    bf16_t* packw = (bf16_t*)(dsts_s + N_EDGES);
    bf16_t* W1t0  = packw;
    bf16_t* W1t1  = W1t0 + PK_W1;
    bf16_t* W2t0  = W1t1 + PK_W1;
    bf16_t* W2t1  = W2t0 + PK_W2;
    bf16_t* CW1t  = W2t1 + PK_W2;
    bf16_t* W0p   = CW1t + PK_CW;
    bf16_t* W1p   = W0p + PK_F0;
    bf16_t* W2p   = W1p + PK_FM;

    hipMemsetAsync(cdelta, 0, N_NODES * 3 * sizeof(float), stream);
    hipMemsetAsync(m_i, 0, (size_t)N_NODES * MDIM * sizeof(float), stream);
    hipMemsetAsync(pooled, 0, (N_GRAPHS * MLP + N_GRAPHS) * sizeof(float), stream);
    hipMemsetAsync(deg, 0, N_NODES * sizeof(int), stream);

    const int* e_src = eidx;
    const int* e_dst = eidx + N_EDGES;
    pack_kernel<<<(PK_TOT + 255) / 256, 256, 0, stream>>>(ew1, eb1, ew2, eb2, cw1,
                                                          f0w, f1w, f2w, packw);
    hist_kernel<<<(N_EDGES + 255) / 256, 256, 0, stream>>>(e_dst, deg);
    scan_kernel<<<1, 1024, 0, stream>>>(deg, cursor);
    scatter_kernel<<<(N_EDGES + 255) / 256, 256, 0, stream>>>(e_src, e_dst, cursor, srcs_s, dsts_s);

    embed_kernel<<<(N_NODES + 255) / 256, 256, 0, stream>>>(z, embt, embw, embb, batch, f0, fb0, cnt);

    const int EBLK = N_EDGES / ETILE; // 6250
    edge_mfma<1><<<EBLK, 256, 0, stream>>>(fb0, pos, srcs_s, dsts_s,
        W1t0, W2t0, CW1t, cb1, cw2, cb2, m_i, cdelta);
    node_kernel<1><<<(N_NODES + 255) / 256, 256, 0, stream>>>(f0, m_i, nw1, nb1, nw2, nb2, f1v, fb1);
    coor_kernel<<<(N_NODES * 3 + 255) / 256, 256, 0, stream>>>(pos, cdelta, coorsA);
    hipMemsetAsync(m_i, 0, (size_t)N_NODES * MDIM * sizeof(float), stream);
    edge_mfma<0><<<EBLK, 256, 0, stream>>>(fb1, coorsA, srcs_s, dsts_s,
        W1t1, W2t1, CW1t, cb1, cw2, cb2, m_i, nullptr);
    node_kernel<0><<<(N_NODES + 255) / 256, 256, 0, stream>>>(f1v, m_i,
        nw1 + NIN * NH, nb1 + NH, nw2 + NH * EMB, nb2 + EMB, f2v, nullptr);

    const int FBLK = (N_NODES + NTILE - 1) / NTILE;
    ffnn_fused<<<FBLK, 512, 0, stream>>>(f0, f1v, f2v, W0p, W1p, W2p,
                                         f0b, f1b, f2b, batch, pooled);

    final_kernel<<<1, 256, 0, stream>>>(pooled, cnt, fow, fob, (float*)d_out);
}

// Round 8
// 963.931 us; speedup vs baseline: 1.3038x; 1.0087x over previous
//
#include <hip/hip_runtime.h>
#include <hip/hip_bf16.h>

#define N_NODES  50000
#define N_EDGES  800000
#define N_GRAPHS 64
#define EMB      24
#define MDIM     64
#define EDGE_IN  57
#define EH       114   // EDGE_IN*2
#define CH       256   // M_DIM*4
#define NIN      88    // EMB+MDIM
#define NH       48    // EMB*2
#define MLP      256
#define ETILE    128
#define NTILE    64

typedef __bf16 bf16_t;
typedef __bf16 bf16x8 __attribute__((ext_vector_type(8)));
typedef __bf16 bf16x4 __attribute__((ext_vector_type(4)));
typedef float  f32x4  __attribute__((ext_vector_type(4)));

__device__ __forceinline__ float siluf(float x) {
    return x * __builtin_amdgcn_rcpf(1.0f + __expf(-x));
}

// packed-f32 silu on 4 lanes: v_pk_mul/add for the vector parts, exp2/rcp trans
__device__ __forceinline__ f32x4 silu4(f32x4 x) {
    f32x4 t = x * (-1.44269504088896341f);   // pk_mul x2
    f32x4 e;
    e[0] = __builtin_amdgcn_exp2f(t[0]);
    e[1] = __builtin_amdgcn_exp2f(t[1]);
    e[2] = __builtin_amdgcn_exp2f(t[2]);
    e[3] = __builtin_amdgcn_exp2f(t[3]);
    f32x4 den = e + 1.0f;                    // pk_add x2
    f32x4 r;
    r[0] = __builtin_amdgcn_rcpf(den[0]);
    r[1] = __builtin_amdgcn_rcpf(den[1]);
    r[2] = __builtin_amdgcn_rcpf(den[2]);
    r[3] = __builtin_amdgcn_rcpf(den[3]);
    return x * r;                            // pk_mul x2
}

// ---------------- embedding: feats0 = emb_table[z] @ emb_w + emb_b ----------
__global__ void embed_kernel(const int* __restrict__ z, const float* __restrict__ table,
                             const float* __restrict__ w, const float* __restrict__ b,
                             const int* __restrict__ batch, float* __restrict__ f0,
                             bf16_t* __restrict__ fb0, float* __restrict__ cnt)
{
    int n = blockIdx.x * blockDim.x + threadIdx.x;
    if (n >= N_NODES) return;
    float r[EMB];
    const float4* tr = reinterpret_cast<const float4*>(table + z[n] * EMB);
    #pragma unroll
    for (int q = 0; q < 6; q++) {
        float4 v = tr[q];
        r[q*4] = v.x; r[q*4+1] = v.y; r[q*4+2] = v.z; r[q*4+3] = v.w;
    }
    float o[EMB];
    #pragma unroll
    for (int j = 0; j < EMB; j++) o[j] = b[j];
    #pragma unroll
    for (int i = 0; i < EMB; i++) {
        #pragma unroll
        for (int j = 0; j < EMB; j++) o[j] = fmaf(r[i], w[i*EMB + j], o[j]);
    }
    float4* dst = reinterpret_cast<float4*>(f0 + (size_t)n * EMB);
    #pragma unroll
    for (int q = 0; q < 6; q++) dst[q] = make_float4(o[q*4], o[q*4+1], o[q*4+2], o[q*4+3]);
    bf16x8* bdst = reinterpret_cast<bf16x8*>(fb0 + (size_t)n * EMB);
    #pragma unroll
    for (int q = 0; q < 3; q++) {
        bf16x8 pk;
        #pragma unroll
        for (int j = 0; j < 8; j++) pk[j] = (bf16_t)o[q*8 + j];
        bdst[q] = pk;
    }
    atomicAdd(&cnt[batch[n]], 1.0f);
}

// ---------------- weight pre-pack to bf16 MFMA layout (A-operand [n][k]) ----
#define PK_W1   (128*64)
#define PK_W2   (64*128)
#define PK_CW   (256*64)
#define PK_F0   (256*128)
#define PK_FM   (256*256)
#define PK_TOT  (2*PK_W1 + 2*PK_W2 + PK_CW + PK_F0 + 2*PK_FM)
__global__ void pack_kernel(const float* __restrict__ ew1, const float* __restrict__ eb1,
                            const float* __restrict__ ew2, const float* __restrict__ eb2,
                            const float* __restrict__ cw1, const float* __restrict__ f0w,
                            const float* __restrict__ f1w, const float* __restrict__ f2w,
                            bf16_t* __restrict__ pw)
{
    int idx = blockIdx.x * blockDim.x + threadIdx.x;
    if (idx >= PK_TOT) return;
    float v = 0.0f;
    if (idx < 2 * PK_W1) {
        int l = idx / PK_W1, r = idx - l * PK_W1;
        int n = r >> 6, k = r & 63;
        if (n < EH && k < EDGE_IN)       v = ew1[(l * EDGE_IN + k) * EH + n];
        else if (n < EH && k == EDGE_IN) v = eb1[l * EH + n];
    } else if (idx < 2 * PK_W1 + 2 * PK_W2) {
        int r0 = idx - 2 * PK_W1;
        int l = r0 / PK_W2, r = r0 - l * PK_W2;
        int n = r >> 7, k = r & 127;
        if (k < EH)       v = ew2[(l * EH + k) * MDIM + n];
        else if (k == EH) v = eb2[l * MDIM + n];
    } else if (idx < 2 * PK_W1 + 2 * PK_W2 + PK_CW) {
        int r = idx - (2 * PK_W1 + 2 * PK_W2);
        int n = r >> 6, k = r & 63;
        v = cw1[k * CH + n];
    } else if (idx < 2 * PK_W1 + 2 * PK_W2 + PK_CW + PK_F0) {
        int r = idx - (2 * PK_W1 + 2 * PK_W2 + PK_CW);
        int n = r >> 7, k = r & 127;
        if (k < 72) v = f0w[k * MLP + n];
    } else {
        int r0 = idx - (2 * PK_W1 + 2 * PK_W2 + PK_CW + PK_F0);
        int l = r0 / PK_FM, r = r0 - l * PK_FM;
        int n = r >> 8, k = r & 255;
        v = (l == 0) ? f1w[k * MLP + n] : f2w[k * MLP + n];
    }
    pw[idx] = (bf16_t)v;
}

// ---------------- CSR build --------------------------------------------------
__global__ void hist_kernel(const int* __restrict__ dst, int* __restrict__ deg)
{
    int e = blockIdx.x * blockDim.x + threadIdx.x;
    if (e < N_EDGES) atomicAdd(&deg[dst[e]], 1);
}

__global__ __launch_bounds__(1024)
void scan_kernel(const int* __restrict__ deg, int* __restrict__ cursor)
{
    __shared__ int part[1024];
    int t = threadIdx.x;
    const int PER = 49;
    int base = t * PER;
    int s = 0;
    for (int i = 0; i < PER; i++) {
        int p = base + i;
        if (p < N_NODES) s += deg[p];
    }
    part[t] = s;
    __syncthreads();
    for (int off = 1; off < 1024; off <<= 1) {
        int add = (t >= off) ? part[t - off] : 0;
        __syncthreads();
        part[t] += add;
        __syncthreads();
    }
    int run = (t > 0) ? part[t - 1] : 0;
    for (int i = 0; i < PER; i++) {
        int p = base + i;
        if (p < N_NODES) { cursor[p] = run; run += deg[p]; }
    }
}

__global__ void scatter_kernel(const int* __restrict__ src, const int* __restrict__ dst,
                               int* __restrict__ cursor, int* __restrict__ srcs_s,
                               int* __restrict__ dsts_s)
{
    int e = blockIdx.x * blockDim.x + threadIdx.x;
    if (e >= N_EDGES) return;
    int d = dst[e];
    int pos = atomicAdd(&cursor[d], 1);
    srcs_s[pos] = src[e];
    dsts_s[pos] = d;
}

// ---------------- fused MFMA edge kernel: WAVE-AUTONOMOUS, ZERO BARRIERS ----
// 256 thr / 4 waves / 128 edges; 8KB LDS slab per wave (union Ein->H1->Mf32).
// pk-f32 epilogues, W1 ks0 register prefetch, setprio around MFMA clusters.
template<int COOR>
__global__ __launch_bounds__(256, 4)
void edge_mfma(const bf16_t* __restrict__ fb, const float* __restrict__ coors,
               const int* __restrict__ srcs_s, const int* __restrict__ dsts_s,
               const bf16_t* __restrict__ W1t, const bf16_t* __restrict__ W2t,
               const bf16_t* __restrict__ CW1t, const float* __restrict__ cb1,
               const float* __restrict__ cw2, const float* __restrict__ cb2,
               float* __restrict__ m_i, float* __restrict__ cdelta)
{
    __shared__ __align__(16) char R1raw[4 * 8192];        // 4 slabs x 8KB
    __shared__ float s_rel[COOR ? ETILE * 3 : 4];
    __shared__ float s_cacc[COOR ? ETILE : 4];
    __shared__ int   s_dst[ETILE];

    const int t = threadIdx.x;
    const int w = t >> 6;
    const int l = t & 63;
    const int row0 = w * 32;
    const int ebase = blockIdx.x * ETILE;
    const int l15 = l & 15, l4 = l >> 4;
    bf16_t* slab16 = (bf16_t*)(R1raw + w * 8192);
    float*  slab32 = (float*) (R1raw + w * 8192);

    // prefetch GEMM1 ks=0 weight fragments (32 VGPR) — in flight during gather
    bf16x8 w1f0[8];
    #pragma unroll
    for (int ft = 0; ft < 8; ft++)
        w1f0[ft] = *(const bf16x8*)&W1t[(ft*16 + l15)*64 + l4*8];

    // ---- gather: 2 threads per edge (own stripe only) ----
    {
        int e_loc = t >> 1, half = t & 1;
        int e_l = e_loc & 31;
        int e = ebase + e_loc;
        int s = srcs_s[e], d = dsts_s[e];
        if (half == 0) {
            s_dst[e_loc] = d;
            const bf16x8* fp = reinterpret_cast<const bf16x8*>(fb + (size_t)d * EMB);
            #pragma unroll
            for (int g = 0; g < 3; g++)
                *(bf16x8*)&slab16[e_l*64 + (g ^ (e_l & 7))*8] = fp[g];
        } else {
            const bf16x8* fp = reinterpret_cast<const bf16x8*>(fb + (size_t)s * EMB);
            #pragma unroll
            for (int g = 0; g < 3; g++)
                *(bf16x8*)&slab16[e_l*64 + ((g + 3) ^ (e_l & 7))*8] = fp[g];
            float rx = coors[s*3+0] - coors[d*3+0];
            float ry = coors[s*3+1] - coors[d*3+1];
            float rz = coors[s*3+2] - coors[d*3+2];
            float d2 = rx*rx + ry*ry + rz*rz;
            if (COOR) { s_rel[e_loc*3+0] = rx; s_rel[e_loc*3+1] = ry; s_rel[e_loc*3+2] = rz; }
            bf16x8 p6, p7;
            p6[0]=(bf16_t)__sinf(d2);        p6[1]=(bf16_t)__sinf(d2*0.5f);
            p6[2]=(bf16_t)__sinf(d2*0.25f);  p6[3]=(bf16_t)__sinf(d2*0.125f);
            p6[4]=(bf16_t)__cosf(d2);        p6[5]=(bf16_t)__cosf(d2*0.5f);
            p6[6]=(bf16_t)__cosf(d2*0.25f);  p6[7]=(bf16_t)__cosf(d2*0.125f);
            p7[0]=(bf16_t)d2; p7[1]=(bf16_t)1.0f;
            p7[2]=(bf16_t)0.f; p7[3]=(bf16_t)0.f; p7[4]=(bf16_t)0.f;
            p7[5]=(bf16_t)0.f; p7[6]=(bf16_t)0.f; p7[7]=(bf16_t)0.f;
            *(bf16x8*)&slab16[e_l*64 + (6 ^ (e_l & 7))*8] = p6;
            *(bf16x8*)&slab16[e_l*64 + (7 ^ (e_l & 7))*8] = p7;
        }
    }
    // no barrier: all subsequent reads are this wave's own slab rows

    // ---- GEMM1: H1^T[f][e] = W1t[f][k] * Ein^T[k][e] ----
    f32x4 acc1[2][8];
    #pragma unroll
    for (int et = 0; et < 2; et++)
        #pragma unroll
        for (int ft = 0; ft < 8; ft++) acc1[et][ft] = (f32x4){0.f,0.f,0.f,0.f};
    __builtin_amdgcn_s_setprio(1);
    #pragma unroll
    for (int ks = 0; ks < 2; ks++) {
        bf16x8 bfrag[2];
        #pragma unroll
        for (int et = 0; et < 2; et++) {
            int e_l = et*16 + l15;
            bfrag[et] = *(const bf16x8*)&slab16[e_l*64 + ((ks*4 + l4) ^ (e_l & 7))*8];
        }
        #pragma unroll
        for (int ft = 0; ft < 8; ft++) {
            bf16x8 a = ks ? *(const bf16x8*)&W1t[(ft*16 + l15)*64 + (4 + l4)*8] : w1f0[ft];
            acc1[0][ft] = __builtin_amdgcn_mfma_f32_16x16x32_bf16(a, bfrag[0], acc1[0][ft], 0, 0, 0);
            acc1[1][ft] = __builtin_amdgcn_mfma_f32_16x16x32_bf16(a, bfrag[1], acc1[1][ft], 0, 0, 0);
        }
    }
    __builtin_amdgcn_s_setprio(0);
    // write H1[e][f] = silu4; f==114 -> 1.0 (GEMM2 bias slot); b64 stores
    #pragma unroll
    for (int et = 0; et < 2; et++)
        #pragma unroll
        for (int ft = 0; ft < 8; ft++) {
            int e_l = et*16 + l15;
            int f0 = ft*16 + l4*4;
            f32x4 hv = silu4(acc1[et][ft]);
            if (f0 == EH - 2) hv[2] = 1.0f;   // EH=114 = 7*16+0*4+2
            bf16x4 pk;
            #pragma unroll
            for (int r4 = 0; r4 < 4; r4++) pk[r4] = (bf16_t)hv[r4];
            *(bf16x4*)&slab16[e_l*128 + ((f0 >> 3) ^ (e_l & 7))*8 + (f0 & 7)] = pk;
        }

    // ---- GEMM2: M^T[f][e] = W2t[f][k] * H1^T[k][e] ----
    f32x4 acc2[2][4];
    #pragma unroll
    for (int et = 0; et < 2; et++)
        #pragma unroll
        for (int ft = 0; ft < 4; ft++) acc2[et][ft] = (f32x4){0.f,0.f,0.f,0.f};
    __builtin_amdgcn_s_setprio(1);
    #pragma unroll
    for (int ks = 0; ks < 4; ks++) {
        bf16x8 bfrag[2];
        #pragma unroll
        for (int et = 0; et < 2; et++) {
            int e_l = et*16 + l15;
            bfrag[et] = *(const bf16x8*)&slab16[e_l*128 + ((ks*4 + l4) ^ (e_l & 7))*8];
        }
        #pragma unroll
        for (int ft = 0; ft < 4; ft++) {
            bf16x8 a = *(const bf16x8*)&W2t[(ft*16 + l15)*128 + (ks*4 + l4)*8];
            acc2[0][ft] = __builtin_amdgcn_mfma_f32_16x16x32_bf16(a, bfrag[0], acc2[0][ft], 0, 0, 0);
            acc2[1][ft] = __builtin_amdgcn_mfma_f32_16x16x32_bf16(a, bfrag[1], acc2[1][ft], 0, 0, 0);
        }
    }
    __builtin_amdgcn_s_setprio(0);
    // write M[e][f] f32 (swizzled 16B granules), b128 stores
    #pragma unroll
    for (int et = 0; et < 2; et++)
        #pragma unroll
        for (int ft = 0; ft < 4; ft++) {
            int e_l = et*16 + l15;
            int f0 = ft*16 + l4*4;
            f32x4 v = silu4(acc2[et][ft]);
            *(f32x4*)&slab32[e_l*64 + (((f0 >> 2) ^ (e_l & 7)) << 2)] = v;
        }

    // ---- m_i run-reduction (dst-sorted; wave's own 32-edge stripe) ----
    {
        int col = l;
        int gsw_base = col >> 2, cw = col & 3;
        int cur = s_dst[row0];
        float run = 0.f;
        for (int i = 0; i < 32; i++) {
            int d = s_dst[row0 + i];
            float v = slab32[i*64 + ((gsw_base ^ (i & 7)) << 2) + cw];
            if (d != cur) { atomicAdd(&m_i[(size_t)cur*64 + col], run); run = 0.f; cur = d; }
            run += v;
        }
        atomicAdd(&m_i[(size_t)cur*64 + col], run);
    }

    // ---- GEMM3 + per-wave run-reduced coor scatter (layer 0 only) ----
    if (COOR) {
        f32x4 csumv0 = (f32x4){0.f,0.f,0.f,0.f};
        f32x4 csumv1 = (f32x4){0.f,0.f,0.f,0.f};
        #pragma unroll
        for (int half = 0; half < 2; half++) {
            f32x4 acc3[2][8];
            #pragma unroll
            for (int et = 0; et < 2; et++)
                #pragma unroll
                for (int ft = 0; ft < 8; ft++) acc3[et][ft] = (f32x4){0.f,0.f,0.f,0.f};
            __builtin_amdgcn_s_setprio(1);
            #pragma unroll
            for (int ks = 0; ks < 2; ks++) {
                bf16x8 bfrag[2];
                #pragma unroll
                for (int et = 0; et < 2; et++) {
                    int e_l = et*16 + l15;
                    int g0 = (ks*4 + l4) * 2;
                    f32x4 lo = *(const f32x4*)&slab32[e_l*64 + ((g0 ^ (e_l & 7)) << 2)];
                    f32x4 hi = *(const f32x4*)&slab32[e_l*64 + (((g0 + 1) ^ (e_l & 7)) << 2)];
                    bf16x8 bk;
                    #pragma unroll
                    for (int j = 0; j < 4; j++) { bk[j] = (bf16_t)lo[j]; bk[j+4] = (bf16_t)hi[j]; }
                    bfrag[et] = bk;
                }
                #pragma unroll
                for (int ft = 0; ft < 8; ft++) {
                    bf16x8 a = *(const bf16x8*)&CW1t[(half*128 + ft*16 + l15)*64 + (ks*4 + l4)*8];
                    acc3[0][ft] = __builtin_amdgcn_mfma_f32_16x16x32_bf16(a, bfrag[0], acc3[0][ft], 0, 0, 0);
                    acc3[1][ft] = __builtin_amdgcn_mfma_f32_16x16x32_bf16(a, bfrag[1], acc3[1][ft], 0, 0, 0);
                }
            }
            __builtin_amdgcn_s_setprio(0);
            #pragma unroll
            for (int ft = 0; ft < 8; ft++) {
                int f0 = half*128 + ft*16 + l4*4;
                f32x4 c1 = *(const f32x4*)&cb1[f0];
                f32x4 w2 = *(const f32x4*)&cw2[f0];
                csumv0 += silu4(acc3[0][ft] + c1) * w2;   // pk_fma chain
                csumv1 += silu4(acc3[1][ft] + c1) * w2;
            }
        }
        float csum0 = (csumv0[0] + csumv0[1]) + (csumv0[2] + csumv0[3]);
        float csum1 = (csumv1[0] + csumv1[1]) + (csumv1[2] + csumv1[3]);
        csum0 += __shfl_xor(csum0, 16);
        csum0 += __shfl_xor(csum0, 32);
        csum1 += __shfl_xor(csum1, 16);
        csum1 += __shfl_xor(csum1, 32);
        float cb2v = cb2[0];
        if (l < 32) {
            s_cacc[row0 + l] = ((l & 16) ? csum1 : csum0) + cb2v;
        }
        if (l < 32) {
            int row = row0 + l;
            int d = s_dst[row];
            bool head = (l == 0) || (s_dst[row - 1] != d);
            if (head) {
                float ax = 0.f, ay = 0.f, az = 0.f;
                int i = l;
                do {
                    int r = row0 + i;
                    float c = s_cacc[r];
                    ax = fmaf(c, s_rel[r*3+0], ax);
                    ay = fmaf(c, s_rel[r*3+1], ay);
                    az = fmaf(c, s_rel[r*3+2], az);
                    ++i;
                } while (i < 32 && s_dst[row0 + i] == d);
                atomicAdd(&cdelta[d*3+0], ax);
                atomicAdd(&cdelta[d*3+1], ay);
                atomicAdd(&cdelta[d*3+2], az);
            }
        }
    }
}

// ---------------- node kernel: feats_out = feats + MLP([feats, m_i]) --------
template<int EMIT_BF16>
__global__ __launch_bounds__(256)
void node_kernel(const float* __restrict__ feats, const float* __restrict__ m_i,
                 const float* __restrict__ nw1, const float* __restrict__ nb1,
                 const float* __restrict__ nw2, const float* __restrict__ nb2,
                 float* __restrict__ fout, bf16_t* __restrict__ fbout)
{
    __shared__ float s_w1t[NH * NIN];
    __shared__ float s_b1[NH];
    __shared__ float s_w2[NH * EMB];
    __shared__ float s_b2[EMB];
    const int tid = threadIdx.x;
    for (int idx = tid; idx < NH * NIN; idx += 256) {
        int k = idx / NIN, i = idx - k * NIN;
        s_w1t[idx] = nw1[i * NH + k];
    }
    for (int idx = tid; idx < NH * EMB; idx += 256) s_w2[idx] = nw2[idx];
    if (tid < NH) s_b1[tid] = nb1[tid];
    if (tid < EMB) s_b2[tid] = nb2[tid];
    __syncthreads();

    int n = blockIdx.x * 256 + tid;
    if (n >= N_NODES) return;

    float in[NIN];
    const float4* fp = reinterpret_cast<const float4*>(feats + (size_t)n * EMB);
    #pragma unroll
    for (int q = 0; q < 6; q++) {
        float4 v = fp[q];
        in[q*4] = v.x; in[q*4+1] = v.y; in[q*4+2] = v.z; in[q*4+3] = v.w;
    }
    const float4* mp = reinterpret_cast<const float4*>(m_i + (size_t)n * MDIM);
    #pragma unroll
    for (int q = 0; q < 16; q++) {
        float4 v = mp[q];
        in[EMB+q*4] = v.x; in[EMB+q*4+1] = v.y; in[EMB+q*4+2] = v.z; in[EMB+q*4+3] = v.w;
    }
    float o[EMB];
    #pragma unroll
    for (int j = 0; j < EMB; j++) o[j] = in[j] + s_b2[j];
    for (int k = 0; k < NH; k++) {
        const float* w1 = &s_w1t[k * NIN];
        float a0 = 0.f, a1 = 0.f, a2 = 0.f, a3 = 0.f;
        #pragma unroll
        for (int i = 0; i < NIN; i += 4) {
            a0 = fmaf(in[i],   w1[i],   a0);
            a1 = fmaf(in[i+1], w1[i+1], a1);
            a2 = fmaf(in[i+2], w1[i+2], a2);
            a3 = fmaf(in[i+3], w1[i+3], a3);
        }
        float h = siluf(s_b1[k] + ((a0 + a1) + (a2 + a3)));
        const float* w2 = &s_w2[k * EMB];
        #pragma unroll
        for (int j = 0; j < EMB; j++) o[j] = fmaf(h, w2[j], o[j]);
    }
    float4* dst = reinterpret_cast<float4*>(fout + (size_t)n * EMB);
    #pragma unroll
    for (int q = 0; q < 6; q++) dst[q] = make_float4(o[q*4], o[q*4+1], o[q*4+2], o[q*4+3]);
    if (EMIT_BF16) {
        bf16x8* bdst = reinterpret_cast<bf16x8*>(fbout + (size_t)n * EMB);
        #pragma unroll
        for (int q = 0; q < 3; q++) {
            bf16x8 pk;
            #pragma unroll
            for (int j = 0; j < 8; j++) pk[j] = (bf16_t)o[q*8 + j];
            bdst[q] = pk;
        }
    }
}

// ---------------- coors update ----------------------------------------------
__global__ void coor_kernel(const float* __restrict__ pos, const float* __restrict__ cdelta,
                            float* __restrict__ out)
{
    int i = blockIdx.x * blockDim.x + threadIdx.x;
    if (i < N_NODES * 3) out[i] = pos[i] + cdelta[i];
}

// ---------------- fused MFMA FFNN: 512 thr / 8 waves (4 M-tiles x 2 N-halves)
__global__ __launch_bounds__(512, 4)
void ffnn_fused(const float* __restrict__ f0, const float* __restrict__ f1,
                const float* __restrict__ f2,
                const bf16_t* __restrict__ W0p, const bf16_t* __restrict__ W1p,
                const bf16_t* __restrict__ W2p,
                const float* __restrict__ b0, const float* __restrict__ b1,
                const float* __restrict__ b2,
                const int* __restrict__ batch, float* __restrict__ pooled)
{
    __shared__ __align__(16) bf16_t sH[NTILE * 256]; // 32KB
    __shared__ int s_batch[NTILE];
    const int t = threadIdx.x;
    const int w = t >> 6, l = t & 63;
    const int l15 = l & 15, q = l >> 4;
    const int mt = w & 3;
    const int nh = w >> 2;
    const int mrow0 = mt * 16;
    const int n0 = blockIdx.x * NTILE;

    // ---- gather x = silu(concat(f0,f1,f2)) -> sH-as-[64][128] bf16 swz ----
    {
        int row = t >> 3, part = t & 7;
        int n = n0 + row;
        bool valid = n < N_NODES;
        if (part == 7) s_batch[row] = valid ? batch[n] : -1;
        #pragma unroll
        for (int gi = 0; gi < 2; gi++) {
            int g = part * 2 + gi;
            bf16x8 pk;
            #pragma unroll
            for (int j = 0; j < 8; j++) pk[j] = (bf16_t)0.f;
            if (valid && g < 9) {
                const float* sp = (g < 3) ? f0 + (size_t)n*EMB + 8*g
                                : (g < 6) ? f1 + (size_t)n*EMB + 8*(g-3)
                                          : f2 + (size_t)n*EMB + 8*(g-6);
                float4 a = ((const float4*)sp)[0], b = ((const float4*)sp)[1];
                f32x4 sa = silu4((f32x4){a.x, a.y, a.z, a.w});
                f32x4 sb = silu4((f32x4){b.x, b.y, b.z, b.w});
                pk[0]=(bf16_t)sa[0]; pk[1]=(bf16_t)sa[1]; pk[2]=(bf16_t)sa[2]; pk[3]=(bf16_t)sa[3];
                pk[4]=(bf16_t)sb[0]; pk[5]=(bf16_t)sb[1]; pk[6]=(bf16_t)sb[2]; pk[7]=(bf16_t)sb[3];
            }
            *(bf16x8*)&sH[row*128 + (g ^ (row & 7))*8] = pk;
        }
    }
    __syncthreads();

    // ---- L0: prefetch A to regs, then h = silu(x @ W0p + b0) ----
    bf16x8 a0[4];
    {
        int r = mrow0 + l15;
        #pragma unroll
        for (int ks = 0; ks < 4; ks++)
            a0[ks] = *(const bf16x8*)&sH[r*128 + ((ks*4 + q) ^ (r & 7))*8];
    }
    __syncthreads();

    f32x4 acc[8];
    #pragma unroll
    for (int nt = 0; nt < 8; nt++) {
        float bv = b0[(nh*8 + nt)*16 + l15];
        acc[nt] = (f32x4){bv, bv, bv, bv};
    }
    #pragma unroll
    for (int ks = 0; ks < 4; ks++)
        #pragma unroll
        for (int nt = 0; nt < 8; nt++) {
            int n = (nh*8 + nt)*16 + l15;
            bf16x8 b = *(const bf16x8*)&W0p[n*128 + (ks*4 + q)*8];
            acc[nt] = __builtin_amdgcn_mfma_f32_16x16x32_bf16(a0[ks], b, acc[nt], 0, 0, 0);
        }
    #pragma unroll
    for (int nt = 0; nt < 8; nt++) {
        f32x4 sv = silu4(acc[nt]);
        #pragma unroll
        for (int r4 = 0; r4 < 4; r4++) {
            int row = mrow0 + q*4 + r4;
            int col = (nh*8 + nt)*16 + l15;
            sH[row*256 + ((col >> 3) ^ (row & 7))*8 + (col & 7)] = (bf16_t)sv[r4];
        }
    }
    __syncthreads();

    // ---- L1 and L2: h = silu(h @ Wp + b) ----
    #pragma unroll
    for (int layer = 0; layer < 2; layer++) {
        const bf16_t* Wp = layer ? W2p : W1p;
        const float*  bb = layer ? b2  : b1;
        #pragma unroll
        for (int nt = 0; nt < 8; nt++) {
            float bv = bb[(nh*8 + nt)*16 + l15];
            acc[nt] = (f32x4){bv, bv, bv, bv};
        }
        for (int ks = 0; ks < 8; ks++) {
            int r = mrow0 + l15;
            bf16x8 a = *(const bf16x8*)&sH[r*256 + ((ks*4 + q) ^ (r & 7))*8];
            #pragma unroll
            for (int nt = 0; nt < 8; nt++) {
                int n = (nh*8 + nt)*16 + l15;
                bf16x8 b = *(const bf16x8*)&Wp[n*256 + (ks*4 + q)*8];
                acc[nt] = __builtin_amdgcn_mfma_f32_16x16x32_bf16(a, b, acc[nt], 0, 0, 0);
            }
        }
        __syncthreads();
        #pragma unroll
        for (int nt = 0; nt < 8; nt++) {
            f32x4 sv = silu4(acc[nt]);
            #pragma unroll
            for (int r4 = 0; r4 < 4; r4++) {
                int row = mrow0 + q*4 + r4;
                int col = (nh*8 + nt)*16 + l15;
                sH[row*256 + ((col >> 3) ^ (row & 7))*8 + (col & 7)] = (bf16_t)sv[r4];
            }
        }
        __syncthreads();
    }

    // ---- fused pooling: 2 row-halves x 256 cols, batch-run reduction ----
    {
        int j = t & 255;
        int rh = t >> 8;
        int g = j >> 3, jo = j & 7;
        int cur = -1;
        float run = 0.f;
        for (int i = rh*32; i < rh*32 + 32; i++) {
            int bb = s_batch[i];
            if (bb != cur) {
                if (cur >= 0) atomicAdd(&pooled[cur * MLP + j], run);
                run = 0.f; cur = bb;
            }
            if (bb >= 0) run += (float)sH[i*256 + (g ^ (i & 7))*8 + jo];
        }
        if (cur >= 0) atomicAdd(&pooled[cur * MLP + j], run);
    }
}

// ---------------- final: sigmoid((pooled/cnt) @ fow + fob) ------------------
__global__ void final_kernel(const float* __restrict__ pooled, const float* __restrict__ cnt,
                             const float* __restrict__ fow, const float* __restrict__ fob,
                             float* __restrict__ out)
{
    int t = threadIdx.x;
    int bg = t >> 2, o = t & 3;
    float c = fmaxf(cnt[bg], 1.0f);
    float acc = 0.f;
    for (int i = 0; i < MLP; i++) acc = fmaf(pooled[bg * MLP + i], fow[i * 4 + o], acc);
    acc = acc / c + fob[o];
    out[t] = 1.0f / (1.0f + __expf(-acc));
}

extern "C" void kernel_launch(void* const* d_in, const int* in_sizes, int n_in,
                              void* d_out, int out_size, void* d_ws, size_t ws_size,
                              hipStream_t stream)
{
    const int*   z     = (const int*)  d_in[0];
    const float* pos   = (const float*)d_in[1];
    const int*   eidx  = (const int*)  d_in[2];
    const int*   batch = (const int*)  d_in[3];
    const float* embt  = (const float*)d_in[4];
    const float* embw  = (const float*)d_in[5];
    const float* embb  = (const float*)d_in[6];
    const float* ew1   = (const float*)d_in[7];
    const float* eb1   = (const float*)d_in[8];
    const float* ew2   = (const float*)d_in[9];
    const float* eb2   = (const float*)d_in[10];
    const float* cw1   = (const float*)d_in[11];
    const float* cb1   = (const float*)d_in[12];
    const float* cw2   = (const float*)d_in[13];
    const float* cb2   = (const float*)d_in[14];
    const float* nw1   = (const float*)d_in[15];
    const float* nb1   = (const float*)d_in[16];
    const float* nw2   = (const float*)d_in[17];
    const float* nb2   = (const float*)d_in[18];
    const float* f0w   = (const float*)d_in[19];
    const float* f0b   = (const float*)d_in[20];
    const float* f1w   = (const float*)d_in[21];
    const float* f1b   = (const float*)d_in[22];
    const float* f2w   = (const float*)d_in[23];
    const float* f2b   = (const float*)d_in[24];
    const float* fow   = (const float*)d_in[25];
    const float* fob   = (const float*)d_in[26];

    float* ws     = (float*)d_ws;
    float* f0     = ws;
    float* f1v    = f0 + (size_t)N_NODES * EMB;
    float* f2v    = f1v + (size_t)N_NODES * EMB;
    bf16_t* fb0   = (bf16_t*)(f2v + (size_t)N_NODES * EMB);
    bf16_t* fb1   = fb0 + (size_t)N_NODES * EMB;
    float* coorsA = (float*)(fb1 + (size_t)N_NODES * EMB);
    float* cdelta = coorsA + N_NODES * 3;
    float* m_i    = cdelta + N_NODES * 3;
    float* pooled = m_i + (size_t)N_NODES * MDIM;
    float* cnt    = pooled + N_GRAPHS * MLP;
    int*   deg    = (int*)(cnt + N_GRAPHS);
    int*   cursor = deg + N_NODES;
    int*   srcs_s = cursor + N_NODES;
    int*   dsts_s = srcs_s + N_EDGES;
    bf16_t* packw = (bf16_t*)(dsts_s + N_EDGES);
    bf16_t* W1t0  = packw;
    bf16_t* W1t1  = W1t0 + PK_W1;
    bf16_t* W2t0  = W1t1 + PK_W1;
    bf16_t* W2t1  = W2t0 + PK_W2;
    bf16_t* CW1t  = W2t1 + PK_W2;
    bf16_t* W0p   = CW1t + PK_CW;
    bf16_t* W1p   = W0p + PK_F0;
    bf16_t* W2p   = W1p + PK_FM;

    hipMemsetAsync(cdelta, 0, N_NODES * 3 * sizeof(float), stream);
    hipMemsetAsync(m_i, 0, (size_t)N_NODES * MDIM * sizeof(float), stream);
    hipMemsetAsync(pooled, 0, (N_GRAPHS * MLP + N_GRAPHS) * sizeof(float), stream);
    hipMemsetAsync(deg, 0, N_NODES * sizeof(int), stream);

    const int* e_src = eidx;
    const int* e_dst = eidx + N_EDGES;
    pack_kernel<<<(PK_TOT + 255) / 256, 256, 0, stream>>>(ew1, eb1, ew2, eb2, cw1,
                                                          f0w, f1w, f2w, packw);
    hist_kernel<<<(N_EDGES + 255) / 256, 256, 0, stream>>>(e_dst, deg);
    scan_kernel<<<1, 1024, 0, stream>>>(deg, cursor);
    scatter_kernel<<<(N_EDGES + 255) / 256, 256, 0, stream>>>(e_src, e_dst, cursor, srcs_s, dsts_s);

    embed_kernel<<<(N_NODES + 255) / 256, 256, 0, stream>>>(z, embt, embw, embb, batch, f0, fb0, cnt);

    const int EBLK = N_EDGES / ETILE; // 6250
    edge_mfma<1><<<EBLK, 256, 0, stream>>>(fb0, pos, srcs_s, dsts_s,
        W1t0, W2t0, CW1t, cb1, cw2, cb2, m_i, cdelta);
    node_kernel<1><<<(N_NODES + 255) / 256, 256, 0, stream>>>(f0, m_i, nw1, nb1, nw2, nb2, f1v, fb1);
    coor_kernel<<<(N_NODES * 3 + 255) / 256, 256, 0, stream>>>(pos, cdelta, coorsA);
    hipMemsetAsync(m_i, 0, (size_t)N_NODES * MDIM * sizeof(float), stream);
    edge_mfma<0><<<EBLK, 256, 0, stream>>>(fb1, coorsA, srcs_s, dsts_s,
        W1t1, W2t1, CW1t, cb1, cw2, cb2, m_i, nullptr);
    node_kernel<0><<<(N_NODES + 255) / 256, 256, 0, stream>>>(f1v, m_i,
        nw1 + NIN * NH, nb1 + NH, nw2 + NH * EMB, nb2 + EMB, f2v, nullptr);

    const int FBLK = (N_NODES + NTILE - 1) / NTILE;
    ffnn_fused<<<FBLK, 512, 0, stream>>>(f0, f1v, f2v, W0p, W1p, W2p,
                                         f0b, f1b, f2b, batch, pooled);

    final_kernel<<<1, 256, 0, stream>>>(pooled, cnt, fow, fob, (float*)d_out);
}

// Round 9
// 959.368 us; speedup vs baseline: 1.3100x; 1.0048x over previous
//
#include <hip/hip_runtime.h>
#include <hip/hip_bf16.h>

#define N_NODES  50000
#define N_EDGES  800000
#define N_GRAPHS 64
#define EMB      24
#define MDIM     64
#define EDGE_IN  57
#define EH       114   // EDGE_IN*2
#define CH       256   // M_DIM*4
#define NIN      88    // EMB+MDIM
#define NH       48    // EMB*2
#define MLP      256
#define ETILE    128
#define NTILE    64

typedef __bf16 bf16_t;
typedef __bf16 bf16x8 __attribute__((ext_vector_type(8)));
typedef __bf16 bf16x4 __attribute__((ext_vector_type(4)));
typedef float  f32x4  __attribute__((ext_vector_type(4)));

__device__ __forceinline__ float siluf(float x) {
    return x * __builtin_amdgcn_rcpf(1.0f + __expf(-x));
}

__device__ __forceinline__ f32x4 silu4(f32x4 x) {
    f32x4 t = x * (-1.44269504088896341f);
    f32x4 e;
    e[0] = __builtin_amdgcn_exp2f(t[0]);
    e[1] = __builtin_amdgcn_exp2f(t[1]);
    e[2] = __builtin_amdgcn_exp2f(t[2]);
    e[3] = __builtin_amdgcn_exp2f(t[3]);
    f32x4 den = e + 1.0f;
    f32x4 r;
    r[0] = __builtin_amdgcn_rcpf(den[0]);
    r[1] = __builtin_amdgcn_rcpf(den[1]);
    r[2] = __builtin_amdgcn_rcpf(den[2]);
    r[3] = __builtin_amdgcn_rcpf(den[3]);
    return x * r;
}

__device__ __forceinline__ bf16x8 cat44(bf16x4 a, bf16x4 b) {
    bf16x8 r;
    r[0]=a[0]; r[1]=a[1]; r[2]=a[2]; r[3]=a[3];
    r[4]=b[0]; r[5]=b[1]; r[6]=b[2]; r[7]=b[3];
    return r;
}

// ---------------- embedding: feats0 = emb_table[z] @ emb_w + emb_b ----------
__global__ void embed_kernel(const int* __restrict__ z, const float* __restrict__ table,
                             const float* __restrict__ w, const float* __restrict__ b,
                             const int* __restrict__ batch, float* __restrict__ f0,
                             bf16_t* __restrict__ fb0, float* __restrict__ cnt)
{
    int n = blockIdx.x * blockDim.x + threadIdx.x;
    if (n >= N_NODES) return;
    float r[EMB];
    const float4* tr = reinterpret_cast<const float4*>(table + z[n] * EMB);
    #pragma unroll
    for (int q = 0; q < 6; q++) {
        float4 v = tr[q];
        r[q*4] = v.x; r[q*4+1] = v.y; r[q*4+2] = v.z; r[q*4+3] = v.w;
    }
    float o[EMB];
    #pragma unroll
    for (int j = 0; j < EMB; j++) o[j] = b[j];
    #pragma unroll
    for (int i = 0; i < EMB; i++) {
        #pragma unroll
        for (int j = 0; j < EMB; j++) o[j] = fmaf(r[i], w[i*EMB + j], o[j]);
    }
    float4* dst = reinterpret_cast<float4*>(f0 + (size_t)n * EMB);
    #pragma unroll
    for (int q = 0; q < 6; q++) dst[q] = make_float4(o[q*4], o[q*4+1], o[q*4+2], o[q*4+3]);
    bf16x8* bdst = reinterpret_cast<bf16x8*>(fb0 + (size_t)n * EMB);
    #pragma unroll
    for (int q = 0; q < 3; q++) {
        bf16x8 pk;
        #pragma unroll
        for (int j = 0; j < 8; j++) pk[j] = (bf16_t)o[q*8 + j];
        bdst[q] = pk;
    }
    atomicAdd(&cnt[batch[n]], 1.0f);
}

// ---------------- weight pre-pack to bf16 MFMA layout (A-operand [n][k]) ----
// W2t/CW1t use the K-permutation  k_phys=32ks+8g+j -> f=16*(2ks+(j>>2))+4g+(j&3)
// so GEMM2/GEMM3 B-fragments come straight from D-fragment registers.
#define PK_W1   (128*64)
#define PK_W2   (64*128)
#define PK_CW   (256*64)
#define PK_F0   (256*128)
#define PK_FM   (256*256)
#define PK_TOT  (2*PK_W1 + 2*PK_W2 + PK_CW + PK_F0 + 2*PK_FM)
__global__ void pack_kernel(const float* __restrict__ ew1, const float* __restrict__ eb1,
                            const float* __restrict__ ew2, const float* __restrict__ eb2,
                            const float* __restrict__ cw1, const float* __restrict__ f0w,
                            const float* __restrict__ f1w, const float* __restrict__ f2w,
                            bf16_t* __restrict__ pw)
{
    int idx = blockIdx.x * blockDim.x + threadIdx.x;
    if (idx >= PK_TOT) return;
    float v = 0.0f;
    if (idx < 2 * PK_W1) {
        int l = idx / PK_W1, r = idx - l * PK_W1;
        int n = r >> 6, k = r & 63;
        if (n < EH && k < EDGE_IN)       v = ew1[(l * EDGE_IN + k) * EH + n];
        else if (n < EH && k == EDGE_IN) v = eb1[l * EH + n];
    } else if (idx < 2 * PK_W1 + 2 * PK_W2) {
        int r0 = idx - 2 * PK_W1;
        int l = r0 / PK_W2, r = r0 - l * PK_W2;
        int n = r >> 7, kp = r & 127;
        int ks = kp >> 5, g = (kp >> 3) & 3, j = kp & 7;
        int f = 16 * (2*ks + (j >> 2)) + 4*g + (j & 3);
        if (f < EH)       v = ew2[(l * EH + f) * MDIM + n];
        else if (f == EH) v = eb2[l * MDIM + n];
    } else if (idx < 2 * PK_W1 + 2 * PK_W2 + PK_CW) {
        int r = idx - (2 * PK_W1 + 2 * PK_W2);
        int n = r >> 6, kp = r & 63;
        int ks = kp >> 5, g = (kp >> 3) & 3, j = kp & 7;
        int f = 16 * (2*ks + (j >> 2)) + 4*g + (j & 3);
        v = cw1[f * CH + n];
    } else if (idx < 2 * PK_W1 + 2 * PK_W2 + PK_CW + PK_F0) {
        int r = idx - (2 * PK_W1 + 2 * PK_W2 + PK_CW);
        int n = r >> 7, k = r & 127;
        if (k < 72) v = f0w[k * MLP + n];
    } else {
        int r0 = idx - (2 * PK_W1 + 2 * PK_W2 + PK_CW + PK_F0);
        int l = r0 / PK_FM, r = r0 - l * PK_FM;
        int n = r >> 8, k = r & 255;
        v = (l == 0) ? f1w[k * MLP + n] : f2w[k * MLP + n];
    }
    pw[idx] = (bf16_t)v;
}

// ---------------- CSR build --------------------------------------------------
__global__ void hist_kernel(const int* __restrict__ dst, int* __restrict__ deg)
{
    int e = blockIdx.x * blockDim.x + threadIdx.x;
    if (e < N_EDGES) atomicAdd(&deg[dst[e]], 1);
}

__global__ __launch_bounds__(1024)
void scan_kernel(const int* __restrict__ deg, int* __restrict__ cursor)
{
    __shared__ int part[1024];
    int t = threadIdx.x;
    const int PER = 49;
    int base = t * PER;
    int s = 0;
    for (int i = 0; i < PER; i++) {
        int p = base + i;
        if (p < N_NODES) s += deg[p];
    }
    part[t] = s;
    __syncthreads();
    for (int off = 1; off < 1024; off <<= 1) {
        int add = (t >= off) ? part[t - off] : 0;
        __syncthreads();
        part[t] += add;
        __syncthreads();
    }
    int run = (t > 0) ? part[t - 1] : 0;
    for (int i = 0; i < PER; i++) {
        int p = base + i;
        if (p < N_NODES) { cursor[p] = run; run += deg[p]; }
    }
}

__global__ void scatter_kernel(const int* __restrict__ src, const int* __restrict__ dst,
                               int* __restrict__ cursor, int* __restrict__ srcs_s,
                               int* __restrict__ dsts_s)
{
    int e = blockIdx.x * blockDim.x + threadIdx.x;
    if (e >= N_EDGES) return;
    int d = dst[e];
    int pos = atomicAdd(&cursor[d], 1);
    srcs_s[pos] = src[e];
    dsts_s[pos] = d;
}

// ---------------- fused MFMA edge kernel: register-chained GEMMs ------------
// 256 thr / 4 waves / 128 edges; 8KB LDS slab per wave (union Ein -> Mf32).
// H1 and M never round-trip LDS for GEMM inputs: K-permuted weight packing
// makes GEMM2/GEMM3 B-fragments = concatenations of held D-fragment regs.
// Wave-autonomous, zero barriers.
template<int COOR>
__global__ __launch_bounds__(256, 4)
void edge_mfma(const bf16_t* __restrict__ fb, const float* __restrict__ coors,
               const int* __restrict__ srcs_s, const int* __restrict__ dsts_s,
               const bf16_t* __restrict__ W1t, const bf16_t* __restrict__ W2t,
               const bf16_t* __restrict__ CW1t, const float* __restrict__ cb1,
               const float* __restrict__ cw2, const float* __restrict__ cb2,
               float* __restrict__ m_i, float* __restrict__ cdelta)
{
    __shared__ __align__(16) char R1raw[4 * 8192];        // 4 slabs x 8KB
    __shared__ float s_rel[COOR ? ETILE * 3 : 4];
    __shared__ float s_cacc[COOR ? ETILE : 4];
    __shared__ int   s_dst[ETILE];

    const int t = threadIdx.x;
    const int w = t >> 6;
    const int l = t & 63;
    const int row0 = w * 32;
    const int ebase = blockIdx.x * ETILE;
    const int l15 = l & 15, l4 = l >> 4;
    bf16_t* slab16 = (bf16_t*)(R1raw + w * 8192);
    float*  slab32 = (float*) (R1raw + w * 8192);

    // ---- gather: 2 threads per edge (own stripe only) ----
    {
        int e_loc = t >> 1, half = t & 1;
        int e_l = e_loc & 31;
        int e = ebase + e_loc;
        int s = srcs_s[e], d = dsts_s[e];
        if (half == 0) {
            s_dst[e_loc] = d;
            const bf16x8* fp = reinterpret_cast<const bf16x8*>(fb + (size_t)d * EMB);
            #pragma unroll
            for (int g = 0; g < 3; g++)
                *(bf16x8*)&slab16[e_l*64 + (g ^ (e_l & 7))*8] = fp[g];
        } else {
            const bf16x8* fp = reinterpret_cast<const bf16x8*>(fb + (size_t)s * EMB);
            #pragma unroll
            for (int g = 0; g < 3; g++)
                *(bf16x8*)&slab16[e_l*64 + ((g + 3) ^ (e_l & 7))*8] = fp[g];
            float rx = coors[s*3+0] - coors[d*3+0];
            float ry = coors[s*3+1] - coors[d*3+1];
            float rz = coors[s*3+2] - coors[d*3+2];
            float d2 = rx*rx + ry*ry + rz*rz;
            if (COOR) { s_rel[e_loc*3+0] = rx; s_rel[e_loc*3+1] = ry; s_rel[e_loc*3+2] = rz; }
            bf16x8 p6, p7;
            p6[0]=(bf16_t)__sinf(d2);        p6[1]=(bf16_t)__sinf(d2*0.5f);
            p6[2]=(bf16_t)__sinf(d2*0.25f);  p6[3]=(bf16_t)__sinf(d2*0.125f);
            p6[4]=(bf16_t)__cosf(d2);        p6[5]=(bf16_t)__cosf(d2*0.5f);
            p6[6]=(bf16_t)__cosf(d2*0.25f);  p6[7]=(bf16_t)__cosf(d2*0.125f);
            p7[0]=(bf16_t)d2; p7[1]=(bf16_t)1.0f;
            p7[2]=(bf16_t)0.f; p7[3]=(bf16_t)0.f; p7[4]=(bf16_t)0.f;
            p7[5]=(bf16_t)0.f; p7[6]=(bf16_t)0.f; p7[7]=(bf16_t)0.f;
            *(bf16x8*)&slab16[e_l*64 + (6 ^ (e_l & 7))*8] = p6;
            *(bf16x8*)&slab16[e_l*64 + (7 ^ (e_l & 7))*8] = p7;
        }
    }
    // no barrier: all LDS reads below are this wave's own slab

    // ---- GEMM1: H1^T[f][e] = W1t[f][k] * Ein^T[k][e] ----
    f32x4 acc1[2][8];
    #pragma unroll
    for (int et = 0; et < 2; et++)
        #pragma unroll
        for (int ft = 0; ft < 8; ft++) acc1[et][ft] = (f32x4){0.f,0.f,0.f,0.f};
    __builtin_amdgcn_s_setprio(1);
    #pragma unroll
    for (int ks = 0; ks < 2; ks++) {
        bf16x8 bfrag[2];
        #pragma unroll
        for (int et = 0; et < 2; et++) {
            int e_l = et*16 + l15;
            bfrag[et] = *(const bf16x8*)&slab16[e_l*64 + ((ks*4 + l4) ^ (e_l & 7))*8];
        }
        #pragma unroll
        for (int ft = 0; ft < 8; ft++) {
            bf16x8 a = *(const bf16x8*)&W1t[(ft*16 + l15)*64 + (ks*4 + l4)*8];
            acc1[0][ft] = __builtin_amdgcn_mfma_f32_16x16x32_bf16(a, bfrag[0], acc1[0][ft], 0, 0, 0);
            acc1[1][ft] = __builtin_amdgcn_mfma_f32_16x16x32_bf16(a, bfrag[1], acc1[1][ft], 0, 0, 0);
        }
    }
    __builtin_amdgcn_s_setprio(0);

    // H1 = silu (registers only); logical f==114 (ft=7,l4=0,r=2) -> 1.0
    bf16x4 h1b[2][8];
    #pragma unroll
    for (int et = 0; et < 2; et++)
        #pragma unroll
        for (int ft = 0; ft < 8; ft++) {
            f32x4 hv = silu4(acc1[et][ft]);
            if (ft == 7 && l4 == 0) hv[2] = 1.0f;
            bf16x4 pk;
            #pragma unroll
            for (int r4 = 0; r4 < 4; r4++) pk[r4] = (bf16_t)hv[r4];
            h1b[et][ft] = pk;
        }

    // ---- GEMM2: M^T = W2t(perm) * H1^T ; B from registers ----
    f32x4 acc2[2][4];
    #pragma unroll
    for (int et = 0; et < 2; et++)
        #pragma unroll
        for (int ft = 0; ft < 4; ft++) acc2[et][ft] = (f32x4){0.f,0.f,0.f,0.f};
    __builtin_amdgcn_s_setprio(1);
    #pragma unroll
    for (int ks = 0; ks < 4; ks++) {
        bf16x8 bfrag0 = cat44(h1b[0][2*ks], h1b[0][2*ks+1]);
        bf16x8 bfrag1 = cat44(h1b[1][2*ks], h1b[1][2*ks+1]);
        #pragma unroll
        for (int ft = 0; ft < 4; ft++) {
            bf16x8 a = *(const bf16x8*)&W2t[(ft*16 + l15)*128 + (ks*4 + l4)*8];
            acc2[0][ft] = __builtin_amdgcn_mfma_f32_16x16x32_bf16(a, bfrag0, acc2[0][ft], 0, 0, 0);
            acc2[1][ft] = __builtin_amdgcn_mfma_f32_16x16x32_bf16(a, bfrag1, acc2[1][ft], 0, 0, 0);
        }
    }
    __builtin_amdgcn_s_setprio(0);

    // M = silu: f32 to LDS (for m_i reduction) + bf16 regs (GEMM3 B)
    bf16x4 mb[2][4];
    #pragma unroll
    for (int et = 0; et < 2; et++)
        #pragma unroll
        for (int ft = 0; ft < 4; ft++) {
            int e_l = et*16 + l15;
            int f0 = ft*16 + l4*4;
            f32x4 mv = silu4(acc2[et][ft]);
            *(f32x4*)&slab32[e_l*64 + (((f0 >> 2) ^ (e_l & 7)) << 2)] = mv;
            if (COOR) {
                bf16x4 pk;
                #pragma unroll
                for (int r4 = 0; r4 < 4; r4++) pk[r4] = (bf16_t)mv[r4];
                mb[et][ft] = pk;
            }
        }

    // ---- m_i run-reduction (dst-sorted; wave's own 32-edge stripe) ----
    {
        int col = l;
        int gsw_base = col >> 2, cw = col & 3;
        int cur = s_dst[row0];
        float run = 0.f;
        for (int i = 0; i < 32; i++) {
            int d = s_dst[row0 + i];
            float v = slab32[i*64 + ((gsw_base ^ (i & 7)) << 2) + cw];
            if (d != cur) { atomicAdd(&m_i[(size_t)cur*64 + col], run); run = 0.f; cur = d; }
            run += v;
        }
        atomicAdd(&m_i[(size_t)cur*64 + col], run);
    }

    // ---- GEMM3 (B from registers) + per-wave run-reduced coor scatter ----
    if (COOR) {
        f32x4 csumv0 = (f32x4){0.f,0.f,0.f,0.f};
        f32x4 csumv1 = (f32x4){0.f,0.f,0.f,0.f};
        #pragma unroll
        for (int half = 0; half < 2; half++) {
            f32x4 acc3[2][8];
            #pragma unroll
            for (int et = 0; et < 2; et++)
                #pragma unroll
                for (int ft = 0; ft < 8; ft++) acc3[et][ft] = (f32x4){0.f,0.f,0.f,0.f};
            __builtin_amdgcn_s_setprio(1);
            #pragma unroll
            for (int ks = 0; ks < 2; ks++) {
                bf16x8 bfrag0 = cat44(mb[0][2*ks], mb[0][2*ks+1]);
                bf16x8 bfrag1 = cat44(mb[1][2*ks], mb[1][2*ks+1]);
                #pragma unroll
                for (int ft = 0; ft < 8; ft++) {
                    bf16x8 a = *(const bf16x8*)&CW1t[(half*128 + ft*16 + l15)*64 + (ks*4 + l4)*8];
                    acc3[0][ft] = __builtin_amdgcn_mfma_f32_16x16x32_bf16(a, bfrag0, acc3[0][ft], 0, 0, 0);
                    acc3[1][ft] = __builtin_amdgcn_mfma_f32_16x16x32_bf16(a, bfrag1, acc3[1][ft], 0, 0, 0);
                }
            }
            __builtin_amdgcn_s_setprio(0);
            #pragma unroll
            for (int ft = 0; ft < 8; ft++) {
                int f0 = half*128 + ft*16 + l4*4;
                f32x4 c1 = *(const f32x4*)&cb1[f0];
                f32x4 w2 = *(const f32x4*)&cw2[f0];
                csumv0 += silu4(acc3[0][ft] + c1) * w2;
                csumv1 += silu4(acc3[1][ft] + c1) * w2;
            }
        }
        float csum0 = (csumv0[0] + csumv0[1]) + (csumv0[2] + csumv0[3]);
        float csum1 = (csumv1[0] + csumv1[1]) + (csumv1[2] + csumv1[3]);
        csum0 += __shfl_xor(csum0, 16);
        csum0 += __shfl_xor(csum0, 32);
        csum1 += __shfl_xor(csum1, 16);
        csum1 += __shfl_xor(csum1, 32);
        float cb2v = cb2[0];
        if (l < 32) {
            s_cacc[row0 + l] = ((l & 16) ? csum1 : csum0) + cb2v;
        }
        if (l < 32) {
            int row = row0 + l;
            int d = s_dst[row];
            bool head = (l == 0) || (s_dst[row - 1] != d);
            if (head) {
                float ax = 0.f, ay = 0.f, az = 0.f;
                int i = l;
                do {
                    int r = row0 + i;
                    float c = s_cacc[r];
                    ax = fmaf(c, s_rel[r*3+0], ax);
                    ay = fmaf(c, s_rel[r*3+1], ay);
                    az = fmaf(c, s_rel[r*3+2], az);
                    ++i;
                } while (i < 32 && s_dst[row0 + i] == d);
                atomicAdd(&cdelta[d*3+0], ax);
                atomicAdd(&cdelta[d*3+1], ay);
                atomicAdd(&cdelta[d*3+2], az);
            }
        }
    }
}

// ---------------- node kernel: feats_out = feats + MLP([feats, m_i]) --------
template<int EMIT_BF16>
__global__ __launch_bounds__(256)
void node_kernel(const float* __restrict__ feats, const float* __restrict__ m_i,
                 const float* __restrict__ nw1, const float* __restrict__ nb1,
                 const float* __restrict__ nw2, const float* __restrict__ nb2,
                 float* __restrict__ fout, bf16_t* __restrict__ fbout)
{
    __shared__ float s_w1t[NH * NIN];
    __shared__ float s_b1[NH];
    __shared__ float s_w2[NH * EMB];
    __shared__ float s_b2[EMB];
    const int tid = threadIdx.x;
    for (int idx = tid; idx < NH * NIN; idx += 256) {
        int k = idx / NIN, i = idx - k * NIN;
        s_w1t[idx] = nw1[i * NH + k];
    }
    for (int idx = tid; idx < NH * EMB; idx += 256) s_w2[idx] = nw2[idx];
    if (tid < NH) s_b1[tid] = nb1[tid];
    if (tid < EMB) s_b2[tid] = nb2[tid];
    __syncthreads();

    int n = blockIdx.x * 256 + tid;
    if (n >= N_NODES) return;

    float in[NIN];
    const float4* fp = reinterpret_cast<const float4*>(feats + (size_t)n * EMB);
    #pragma unroll
    for (int q = 0; q < 6; q++) {
        float4 v = fp[q];
        in[q*4] = v.x; in[q*4+1] = v.y; in[q*4+2] = v.z; in[q*4+3] = v.w;
    }
    const float4* mp = reinterpret_cast<const float4*>(m_i + (size_t)n * MDIM);
    #pragma unroll
    for (int q = 0; q < 16; q++) {
        float4 v = mp[q];
        in[EMB+q*4] = v.x; in[EMB+q*4+1] = v.y; in[EMB+q*4+2] = v.z; in[EMB+q*4+3] = v.w;
    }
    float o[EMB];
    #pragma unroll
    for (int j = 0; j < EMB; j++) o[j] = in[j] + s_b2[j];
    for (int k = 0; k < NH; k++) {
        const float* w1 = &s_w1t[k * NIN];
        float a0 = 0.f, a1 = 0.f, a2 = 0.f, a3 = 0.f;
        #pragma unroll
        for (int i = 0; i < NIN; i += 4) {
            a0 = fmaf(in[i],   w1[i],   a0);
            a1 = fmaf(in[i+1], w1[i+1], a1);
            a2 = fmaf(in[i+2], w1[i+2], a2);
            a3 = fmaf(in[i+3], w1[i+3], a3);
        }
        float h = siluf(s_b1[k] + ((a0 + a1) + (a2 + a3)));
        const float* w2 = &s_w2[k * EMB];
        #pragma unroll
        for (int j = 0; j < EMB; j++) o[j] = fmaf(h, w2[j], o[j]);
    }
    float4* dst = reinterpret_cast<float4*>(fout + (size_t)n * EMB);
    #pragma unroll
    for (int q = 0; q < 6; q++) dst[q] = make_float4(o[q*4], o[q*4+1], o[q*4+2], o[q*4+3]);
    if (EMIT_BF16) {
        bf16x8* bdst = reinterpret_cast<bf16x8*>(fbout + (size_t)n * EMB);
        #pragma unroll
        for (int q = 0; q < 3; q++) {
            bf16x8 pk;
            #pragma unroll
            for (int j = 0; j < 8; j++) pk[j] = (bf16_t)o[q*8 + j];
            bdst[q] = pk;
        }
    }
}

// ---------------- coors update ----------------------------------------------
__global__ void coor_kernel(const float* __restrict__ pos, const float* __restrict__ cdelta,
                            float* __restrict__ out)
{
    int i = blockIdx.x * blockDim.x + threadIdx.x;
    if (i < N_NODES * 3) out[i] = pos[i] + cdelta[i];
}

// ---------------- fused MFMA FFNN: 512 thr / 8 waves (4 M-tiles x 2 N-halves)
__global__ __launch_bounds__(512, 4)
void ffnn_fused(const float* __restrict__ f0, const float* __restrict__ f1,
                const float* __restrict__ f2,
                const bf16_t* __restrict__ W0p, const bf16_t* __restrict__ W1p,
                const bf16_t* __restrict__ W2p,
                const float* __restrict__ b0, const float* __restrict__ b1,
                const float* __restrict__ b2,
                const int* __restrict__ batch, float* __restrict__ pooled)
{
    __shared__ __align__(16) bf16_t sH[NTILE * 256]; // 32KB
    __shared__ int s_batch[NTILE];
    const int t = threadIdx.x;
    const int w = t >> 6, l = t & 63;
    const int l15 = l & 15, q = l >> 4;
    const int mt = w & 3;
    const int nh = w >> 2;
    const int mrow0 = mt * 16;
    const int n0 = blockIdx.x * NTILE;

    {
        int row = t >> 3, part = t & 7;
        int n = n0 + row;
        bool valid = n < N_NODES;
        if (part == 7) s_batch[row] = valid ? batch[n] : -1;
        #pragma unroll
        for (int gi = 0; gi < 2; gi++) {
            int g = part * 2 + gi;
            bf16x8 pk;
            #pragma unroll
            for (int j = 0; j < 8; j++) pk[j] = (bf16_t)0.f;
            if (valid && g < 9) {
                const float* sp = (g < 3) ? f0 + (size_t)n*EMB + 8*g
                                : (g < 6) ? f1 + (size_t)n*EMB + 8*(g-3)
                                          : f2 + (size_t)n*EMB + 8*(g-6);
                float4 a = ((const float4*)sp)[0], b = ((const float4*)sp)[1];
                f32x4 sa = silu4((f32x4){a.x, a.y, a.z, a.w});
                f32x4 sb = silu4((f32x4){b.x, b.y, b.z, b.w});
                pk[0]=(bf16_t)sa[0]; pk[1]=(bf16_t)sa[1]; pk[2]=(bf16_t)sa[2]; pk[3]=(bf16_t)sa[3];
                pk[4]=(bf16_t)sb[0]; pk[5]=(bf16_t)sb[1]; pk[6]=(bf16_t)sb[2]; pk[7]=(bf16_t)sb[3];
            }
            *(bf16x8*)&sH[row*128 + (g ^ (row & 7))*8] = pk;
        }
    }
    __syncthreads();

    bf16x8 a0[4];
    {
        int r = mrow0 + l15;
        #pragma unroll
        for (int ks = 0; ks < 4; ks++)
            a0[ks] = *(const bf16x8*)&sH[r*128 + ((ks*4 + q) ^ (r & 7))*8];
    }
    __syncthreads();

    f32x4 acc[8];
    #pragma unroll
    for (int nt = 0; nt < 8; nt++) {
        float bv = b0[(nh*8 + nt)*16 + l15];
        acc[nt] = (f32x4){bv, bv, bv, bv};
    }
    #pragma unroll
    for (int ks = 0; ks < 4; ks++)
        #pragma unroll
        for (int nt = 0; nt < 8; nt++) {
            int n = (nh*8 + nt)*16 + l15;
            bf16x8 b = *(const bf16x8*)&W0p[n*128 + (ks*4 + q)*8];
            acc[nt] = __builtin_amdgcn_mfma_f32_16x16x32_bf16(a0[ks], b, acc[nt], 0, 0, 0);
        }
    #pragma unroll
    for (int nt = 0; nt < 8; nt++) {
        f32x4 sv = silu4(acc[nt]);
        #pragma unroll
        for (int r4 = 0; r4 < 4; r4++) {
            int row = mrow0 + q*4 + r4;
            int col = (nh*8 + nt)*16 + l15;
            sH[row*256 + ((col >> 3) ^ (row & 7))*8 + (col & 7)] = (bf16_t)sv[r4];
        }
    }
    __syncthreads();

    #pragma unroll
    for (int layer = 0; layer < 2; layer++) {
        const bf16_t* Wp = layer ? W2p : W1p;
        const float*  bb = layer ? b2  : b1;
        #pragma unroll
        for (int nt = 0; nt < 8; nt++) {
            float bv = bb[(nh*8 + nt)*16 + l15];
            acc[nt] = (f32x4){bv, bv, bv, bv};
        }
        for (int ks = 0; ks < 8; ks++) {
            int r = mrow0 + l15;
            bf16x8 a = *(const bf16x8*)&sH[r*256 + ((ks*4 + q) ^ (r & 7))*8];
            #pragma unroll
            for (int nt = 0; nt < 8; nt++) {
                int n = (nh*8 + nt)*16 + l15;
                bf16x8 b = *(const bf16x8*)&Wp[n*256 + (ks*4 + q)*8];
                acc[nt] = __builtin_amdgcn_mfma_f32_16x16x32_bf16(a, b, acc[nt], 0, 0, 0);
            }
        }
        __syncthreads();
        #pragma unroll
        for (int nt = 0; nt < 8; nt++) {
            f32x4 sv = silu4(acc[nt]);
            #pragma unroll
            for (int r4 = 0; r4 < 4; r4++) {
                int row = mrow0 + q*4 + r4;
                int col = (nh*8 + nt)*16 + l15;
                sH[row*256 + ((col >> 3) ^ (row & 7))*8 + (col & 7)] = (bf16_t)sv[r4];
            }
        }
        __syncthreads();
    }

    {
        int j = t & 255;
        int rh = t >> 8;
        int g = j >> 3, jo = j & 7;
        int cur = -1;
        float run = 0.f;
        for (int i = rh*32; i < rh*32 + 32; i++) {
            int bb = s_batch[i];
            if (bb != cur) {
                if (cur >= 0) atomicAdd(&pooled[cur * MLP + j], run);
                run = 0.f; cur = bb;
            }
            if (bb >= 0) run += (float)sH[i*256 + (g ^ (i & 7))*8 + jo];
        }
        if (cur >= 0) atomicAdd(&pooled[cur * MLP + j], run);
    }
}

// ---------------- final: sigmoid((pooled/cnt) @ fow + fob) ------------------
__global__ void final_kernel(const float* __restrict__ pooled, const float* __restrict__ cnt,
                             const float* __restrict__ fow, const float* __restrict__ fob,
                             float* __restrict__ out)
{
    int t = threadIdx.x;
    int bg = t >> 2, o = t & 3;
    float c = fmaxf(cnt[bg], 1.0f);
    float acc = 0.f;
    for (int i = 0; i < MLP; i++) acc = fmaf(pooled[bg * MLP + i], fow[i * 4 + o], acc);
    acc = acc / c + fob[o];
    out[t] = 1.0f / (1.0f + __expf(-acc));
}

extern "C" void kernel_launch(void* const* d_in, const int* in_sizes, int n_in,
                              void* d_out, int out_size, void* d_ws, size_t ws_size,
                              hipStream_t stream)
{
    const int*   z     = (const int*)  d_in[0];
    const float* pos   = (const float*)d_in[1];
    const int*   eidx  = (const int*)  d_in[2];
    const int*   batch = (const int*)  d_in[3];
    const float* embt  = (const float*)d_in[4];
    const float* embw  = (const float*)d_in[5];
    const float* embb  = (const float*)d_in[6];
    const float* ew1   = (const float*)d_in[7];
    const float* eb1   = (const float*)d_in[8];
    const float* ew2   = (const float*)d_in[9];
    const float* eb2   = (const float*)d_in[10];
    const float* cw1   = (const float*)d_in[11];
    const float* cb1   = (const float*)d_in[12];
    const float* cw2   = (const float*)d_in[13];
    const float* cb2   = (const float*)d_in[14];
    const float* nw1   = (const float*)d_in[15];
    const float* nb1   = (const float*)d_in[16];
    const float* nw2   = (const float*)d_in[17];
    const float* nb2   = (const float*)d_in[18];
    const float* f0w   = (const float*)d_in[19];
    const float* f0b   = (const float*)d_in[20];
    const float* f1w   = (const float*)d_in[21];
    const float* f1b   = (const float*)d_in[22];
    const float* f2w   = (const float*)d_in[23];
    const float* f2b   = (const float*)d_in[24];
    const float* fow   = (const float*)d_in[25];
    const float* fob   = (const float*)d_in[26];

    float* ws     = (float*)d_ws;
    float* f0     = ws;
    float* f1v    = f0 + (size_t)N_NODES * EMB;
    float* f2v    = f1v + (size_t)N_NODES * EMB;
    bf16_t* fb0   = (bf16_t*)(f2v + (size_t)N_NODES * EMB);
    bf16_t* fb1   = fb0 + (size_t)N_NODES * EMB;
    float* coorsA = (float*)(fb1 + (size_t)N_NODES * EMB);
    float* cdelta = coorsA + N_NODES * 3;
    float* m_i    = cdelta + N_NODES * 3;
    float* pooled = m_i + (size_t)N_NODES * MDIM;
    float* cnt    = pooled + N_GRAPHS * MLP;
    int*   deg    = (int*)(cnt + N_GRAPHS);
    int*   cursor = deg + N_NODES;
    int*   srcs_s = cursor + N_NODES;
    int*   dsts_s = srcs_s + N_EDGES;
    bf16_t* packw = (bf16_t*)(dsts_s + N_EDGES);
    bf16_t* W1t0  = packw;
    bf16_t* W1t1  = W1t0 + PK_W1;
    bf16_t* W2t0  = W1t1 + PK_W1;
    bf16_t* W2t1  = W2t0 + PK_W2;
    bf16_t* CW1t  = W2t1 + PK_W2;
    bf16_t* W0p   = CW1t + PK_CW;
    bf16_t* W1p   = W0p + PK_F0;
    bf16_t* W2p   = W1p + PK_FM;

    hipMemsetAsync(cdelta, 0, N_NODES * 3 * sizeof(float), stream);
    hipMemsetAsync(m_i, 0, (size_t)N_NODES * MDIM * sizeof(float), stream);
    hipMemsetAsync(pooled, 0, (N_GRAPHS * MLP + N_GRAPHS) * sizeof(float), stream);
    hipMemsetAsync(deg, 0, N_NODES * sizeof(int), stream);

    const int* e_src = eidx;
    const int* e_dst = eidx + N_EDGES;
    pack_kernel<<<(PK_TOT + 255) / 256, 256, 0, stream>>>(ew1, eb1, ew2, eb2, cw1,
                                                          f0w, f1w, f2w, packw);
    hist_kernel<<<(N_EDGES + 255) / 256, 256, 0, stream>>>(e_dst, deg);
    scan_kernel<<<1, 1024, 0, stream>>>(deg, cursor);
    scatter_kernel<<<(N_EDGES + 255) / 256, 256, 0, stream>>>(e_src, e_dst, cursor, srcs_s, dsts_s);

    embed_kernel<<<(N_NODES + 255) / 256, 256, 0, stream>>>(z, embt, embw, embb, batch, f0, fb0, cnt);

    const int EBLK = N_EDGES / ETILE; // 6250
    edge_mfma<1><<<EBLK, 256, 0, stream>>>(fb0, pos, srcs_s, dsts_s,
        W1t0, W2t0, CW1t, cb1, cw2, cb2, m_i, cdelta);
    node_kernel<1><<<(N_NODES + 255) / 256, 256, 0, stream>>>(f0, m_i, nw1, nb1, nw2, nb2, f1v, fb1);
    coor_kernel<<<(N_NODES * 3 + 255) / 256, 256, 0, stream>>>(pos, cdelta, coorsA);
    hipMemsetAsync(m_i, 0, (size_t)N_NODES * MDIM * sizeof(float), stream);
    edge_mfma<0><<<EBLK, 256, 0, stream>>>(fb1, coorsA, srcs_s, dsts_s,
        W1t1, W2t1, CW1t, cb1, cw2, cb2, m_i, nullptr);
    node_kernel<0><<<(N_NODES + 255) / 256, 256, 0, stream>>>(f1v, m_i,
        nw1 + NIN * NH, nb1 + NH, nw2 + NH * EMB, nb2 + EMB, f2v, nullptr);

    const int FBLK = (N_NODES + NTILE - 1) / NTILE;
    ffnn_fused<<<FBLK, 512, 0, stream>>>(f0, f1v, f2v, W0p, W1p, W2p,
                                         f0b, f1b, f2b, batch, pooled);

    final_kernel<<<1, 256, 0, stream>>>(pooled, cnt, fow, fob, (float*)d_out);
}